// Round 2
// baseline (1341.551 us; speedup 1.0000x reference)
//
#include <hip/hip_runtime.h>
#include <hip/hip_bf16.h>

// Self-dtype-detecting implementation.
//  probe_dtype: decides whether tensors are stored f32 or bf16 (flag in ws).
//  Every GEMM site is launched in both typed variants; blocks early-exit
//  unless the flag matches. Intermediates stored bf16 (fp32 accumulate).
//
// ws layout (bytes):
//   [0)        int flag
//   [256)      gates: 384 f32
//   [4096)     meas: 4096*24 f32            (ends   397,312)
//   [397,312)  enc:  4096*256 f32           (ends 4,591,616)
//   [4,591,616)  P: 4M bf16 (h1,d2,d4)      (ends 12,980,224)
//   [12,980,224) Q: 2M bf16 (h2,d1,d3)      (ends 17,174,528)  ~16.4 MB

using bf16 = __hip_bfloat16;

__device__ inline float ldf(const float* p, size_t i) { return p[i]; }
__device__ inline float ldf(const bf16* p, size_t i) { return __bfloat162float(p[i]); }
__device__ inline void stf(float* p, size_t i, float v) { p[i] = v; }
__device__ inline void stf(bf16* p, size_t i, float v) { p[i] = __float2bfloat16(v); }

// ---------------- dtype probe on eb1 (1024 logical elems, uniform +-0.0198)
__global__ void probe_dtype(const unsigned short* __restrict__ bits,
                            int* __restrict__ flag) {
  __shared__ int s_big, s_evennz;
  if (threadIdx.x == 0) { s_big = 0; s_evennz = 0; }
  __syncthreads();
  int big = 0, evennz = 0;
  for (int t = threadIdx.x; t < 1024; t += 256) {
    unsigned int u = bits[t];
    float v = __uint_as_float(u << 16);
    float a = fabsf(v);
    if (!(a <= 1.0f)) big = 1;                       // >1 or NaN/Inf -> f32
    if ((t & 1) == 0 && (u & 0x7fffu) != 0) evennz = 1;
  }
  if (big) s_big = 1;          // benign same-value races
  if (evennz) s_evennz = 1;
  __syncthreads();
  if (threadIdx.x == 0) *flag = (!s_big && s_evennz) ? 1 : 0;  // 1 = bf16
}

// ---------------- GEMM: C = act(A @ W + bias). A:MxK, W:KxN row-major.
// 64x64 tile, 256 threads, 4x4/thread, BK=16, fp32 accumulate.
template <typename TA, typename TW, typename TC, int ACT>
__global__ __launch_bounds__(256) void gemm_ba(const int* __restrict__ flag, int want,
                                               const TA* __restrict__ A,
                                               const TW* __restrict__ W,
                                               const TW* __restrict__ bias,
                                               TC* __restrict__ C,
                                               int M, int N, int K) {
  if (*flag != want) return;
  __shared__ float As[16][68];
  __shared__ float Bs[16][68];
  const int tid = threadIdx.x;
  const int bm = blockIdx.y * 64;
  const int bn = blockIdx.x * 64;
  const int ty = tid >> 4, tx = tid & 15;
  const int arow = tid >> 2;
  const int acol = (tid & 3) << 2;
  const int brow = tid >> 4;
  const int bcol = (tid & 15) << 2;

  float acc[4][4] = {};

  for (int k0 = 0; k0 < K; k0 += 16) {
#pragma unroll
    for (int j = 0; j < 4; ++j) {
      int k = k0 + acol + j;
      As[acol + j][arow] = (k < K) ? ldf(A, (size_t)(bm + arow) * K + k) : 0.f;
    }
#pragma unroll
    for (int j = 0; j < 4; ++j) {
      int k = k0 + brow;
      Bs[brow][bcol + j] = (k < K) ? ldf(W, (size_t)k * N + (bn + bcol + j)) : 0.f;
    }
    __syncthreads();
#pragma unroll
    for (int kk = 0; kk < 16; ++kk) {
      const float4 av = *(const float4*)&As[kk][ty * 4];
      const float4 bv = *(const float4*)&Bs[kk][tx * 4];
      acc[0][0] += av.x * bv.x; acc[0][1] += av.x * bv.y; acc[0][2] += av.x * bv.z; acc[0][3] += av.x * bv.w;
      acc[1][0] += av.y * bv.x; acc[1][1] += av.y * bv.y; acc[1][2] += av.y * bv.z; acc[1][3] += av.y * bv.w;
      acc[2][0] += av.z * bv.x; acc[2][1] += av.z * bv.y; acc[2][2] += av.z * bv.z; acc[2][3] += av.z * bv.w;
      acc[3][0] += av.w * bv.x; acc[3][1] += av.w * bv.y; acc[3][2] += av.w * bv.z; acc[3][3] += av.w * bv.w;
    }
    __syncthreads();
  }

#pragma unroll
  for (int ii = 0; ii < 4; ++ii) {
    int m = bm + ty * 4 + ii;
#pragma unroll
    for (int jj = 0; jj < 4; ++jj) {
      int n = bn + tx * 4 + jj;
      float v = acc[ii][jj] + ldf(bias, (size_t)n);
      if (ACT == 0) v = (v >= 0.f) ? v : 0.2f * v;
      else v = tanhf(v);
      stf(C, (size_t)m * N + n, v);
    }
  }
}

// ---------------- Gate precompute (48 Rot gates), dtype branch internal
__global__ void prep_gates(const void* __restrict__ dp, const int* __restrict__ flag,
                           float* __restrict__ gw) {
  int g = threadIdx.x;
  if (g >= 48) return;
  float phi, theta, omega;
  if (*flag == 1) {
    const bf16* p = (const bf16*)dp;
    phi = __bfloat162float(p[g * 3 + 0]);
    theta = __bfloat162float(p[g * 3 + 1]);
    omega = __bfloat162float(p[g * 3 + 2]);
  } else {
    const float* p = (const float*)dp;
    phi = p[g * 3 + 0]; theta = p[g * 3 + 1]; omega = p[g * 3 + 2];
  }
  float c = cosf(0.5f * theta), s = sinf(0.5f * theta);
  float a = 0.5f * (phi + omega), d = 0.5f * (phi - omega);
  float ca = cosf(a), sa = sinf(a), cd = cosf(d), sd = sinf(d);
  float* o = gw + g * 8;
  o[0] =  ca * c; o[1] = -sa * c;
  o[2] = -cd * s; o[3] = -sd * s;
  o[4] =  cd * s; o[5] = -sd * s;
  o[6] =  ca * c; o[7] =  sa * c;
}

__device__ inline float wred(float v) {
#pragma unroll
  for (int o = 32; o > 0; o >>= 1) v += __shfl_down(v, o, 64);
  return v;
}

// ---------------- 8-qubit statevector circuit + Z/X/Y measurements
__global__ __launch_bounds__(256) void circuit_kernel(const float* __restrict__ enc,
                                                      const float* __restrict__ gw,
                                                      float* __restrict__ meas) {
  __shared__ float2 psi[256];
  __shared__ float gsh[384];
  __shared__ float wsum[4];
  __shared__ float partial[4][3];
  const int b = blockIdx.x;
  const int i = threadIdx.x;
  const int lane = i & 63, wid = i >> 6;

  for (int t = i; t < 384; t += 256) gsh[t] = gw[t];

  float v = enc[(size_t)b * 256 + i];
  float ss = wred(v * v);
  if (lane == 0) wsum[wid] = ss;
  __syncthreads();
  float nrm = sqrtf(wsum[0] + wsum[1] + wsum[2] + wsum[3]);
  nrm = fmaxf(nrm, 1e-12f);
  psi[i] = make_float2(v / nrm, 0.f);
  __syncthreads();

  for (int l = 0; l < 6; ++l) {
    for (int q = 0; q < 8; ++q) {
      const float* g = &gsh[(l * 8 + q) * 8];
      const int s = 1 << (7 - q);
      if (!(i & s)) {
        float2 p0 = psi[i], p1 = psi[i | s];
        float2 n0, n1;
        n0.x = g[0] * p0.x - g[1] * p0.y + g[2] * p1.x - g[3] * p1.y;
        n0.y = g[0] * p0.y + g[1] * p0.x + g[2] * p1.y + g[3] * p1.x;
        n1.x = g[4] * p0.x - g[5] * p0.y + g[6] * p1.x - g[7] * p1.y;
        n1.y = g[4] * p0.y + g[5] * p0.x + g[6] * p1.y + g[7] * p1.x;
        psi[i] = n0; psi[i | s] = n1;
      }
      __syncthreads();
    }
    const int r = l % 7 + 1;
    for (int q = 0; q < 8; ++q) {
      const int bc = 7 - q, bt = 7 - ((q + r) & 7);
      if (((i >> bc) & 1) && !((i >> bt) & 1)) {
        int j = i | (1 << bt);
        float2 tmp = psi[i]; psi[i] = psi[j]; psi[j] = tmp;
      }
      __syncthreads();
    }
  }

  float2 p = psi[i];
  float prob = p.x * p.x + p.y * p.y;
  for (int q = 0; q < 8; ++q) {
    const int s = 1 << (7 - q);
    float2 f = psi[i ^ s];
    float re = p.x * f.x + p.y * f.y;
    float im = p.x * f.y - p.y * f.x;
    float zc = wred((i & s) ? -prob : prob);
    float xc = wred(re);
    float yc = wred((i & s) ? -im : im);
    if (lane == 0) { partial[wid][0] = zc; partial[wid][1] = xc; partial[wid][2] = yc; }
    __syncthreads();
    if (i < 3) {
      meas[(size_t)b * 24 + i * 8 + q] =
          partial[0][i] + partial[1][i] + partial[2][i] + partial[3][i];
    }
    __syncthreads();
  }
}

extern "C" void kernel_launch(void* const* d_in, const int* in_sizes, int n_in,
                              void* d_out, int out_size, void* d_ws, size_t ws_size,
                              hipStream_t stream) {
  (void)in_sizes; (void)n_in; (void)out_size; (void)ws_size;
  char* wsb = (char*)d_ws;
  int*   flag = (int*)wsb;
  float* gw   = (float*)(wsb + 256);
  float* meas = (float*)(wsb + 4096);
  float* encf = (float*)(wsb + 397312);
  bf16*  P    = (bf16*)(wsb + 4591616);
  bf16*  Q    = (bf16*)(wsb + 12980224);

  const int M = 4096;

  probe_dtype<<<1, 256, 0, stream>>>((const unsigned short*)d_in[2], flag);
  prep_gates<<<1, 64, 0, stream>>>(d_in[7], flag, gw);

  // ---- encoder
  gemm_ba<float, float, bf16, 0><<<dim3(16, 64), 256, 0, stream>>>(
      flag, 0, (const float*)d_in[0], (const float*)d_in[1], (const float*)d_in[2], P, M, 1024, 2560);
  gemm_ba<bf16, bf16, bf16, 0><<<dim3(16, 64), 256, 0, stream>>>(
      flag, 1, (const bf16*)d_in[0], (const bf16*)d_in[1], (const bf16*)d_in[2], P, M, 1024, 2560);

  gemm_ba<bf16, float, bf16, 0><<<dim3(8, 64), 256, 0, stream>>>(
      flag, 0, P, (const float*)d_in[3], (const float*)d_in[4], Q, M, 512, 1024);
  gemm_ba<bf16, bf16, bf16, 0><<<dim3(8, 64), 256, 0, stream>>>(
      flag, 1, P, (const bf16*)d_in[3], (const bf16*)d_in[4], Q, M, 512, 1024);

  gemm_ba<bf16, float, float, 1><<<dim3(4, 64), 256, 0, stream>>>(
      flag, 0, Q, (const float*)d_in[5], (const float*)d_in[6], encf, M, 256, 512);
  gemm_ba<bf16, bf16, float, 1><<<dim3(4, 64), 256, 0, stream>>>(
      flag, 1, Q, (const bf16*)d_in[5], (const bf16*)d_in[6], encf, M, 256, 512);

  // ---- quantum circuit
  circuit_kernel<<<4096, 256, 0, stream>>>(encf, gw, meas);

  // ---- decoder
  gemm_ba<float, float, bf16, 0><<<dim3(2, 64), 256, 0, stream>>>(
      flag, 0, meas, (const float*)d_in[8], (const float*)d_in[9], Q, M, 128, 24);
  gemm_ba<float, bf16, bf16, 0><<<dim3(2, 64), 256, 0, stream>>>(
      flag, 1, meas, (const bf16*)d_in[8], (const bf16*)d_in[9], Q, M, 128, 24);

  gemm_ba<bf16, float, bf16, 0><<<dim3(4, 64), 256, 0, stream>>>(
      flag, 0, Q, (const float*)d_in[10], (const float*)d_in[11], P, M, 256, 128);
  gemm_ba<bf16, bf16, bf16, 0><<<dim3(4, 64), 256, 0, stream>>>(
      flag, 1, Q, (const bf16*)d_in[10], (const bf16*)d_in[11], P, M, 256, 128);

  gemm_ba<bf16, float, bf16, 0><<<dim3(8, 64), 256, 0, stream>>>(
      flag, 0, P, (const float*)d_in[12], (const float*)d_in[13], Q, M, 512, 256);
  gemm_ba<bf16, bf16, bf16, 0><<<dim3(8, 64), 256, 0, stream>>>(
      flag, 1, P, (const bf16*)d_in[12], (const bf16*)d_in[13], Q, M, 512, 256);

  gemm_ba<bf16, float, bf16, 0><<<dim3(16, 64), 256, 0, stream>>>(
      flag, 0, Q, (const float*)d_in[14], (const float*)d_in[15], P, M, 1024, 512);
  gemm_ba<bf16, bf16, bf16, 0><<<dim3(16, 64), 256, 0, stream>>>(
      flag, 1, Q, (const bf16*)d_in[14], (const bf16*)d_in[15], P, M, 1024, 512);

  gemm_ba<bf16, float, float, 1><<<dim3(40, 64), 256, 0, stream>>>(
      flag, 0, P, (const float*)d_in[16], (const float*)d_in[17], (float*)d_out, M, 2560, 1024);
  gemm_ba<bf16, bf16, bf16, 1><<<dim3(40, 64), 256, 0, stream>>>(
      flag, 1, P, (const bf16*)d_in[16], (const bf16*)d_in[17], (bf16*)d_out, M, 2560, 1024);
}

// Round 3
// 738.042 us; speedup vs baseline: 1.8177x; 1.8177x over previous
//
#include <hip/hip_runtime.h>
#include <hip/hip_bf16.h>

// MFMA-based implementation, dual-dtype (f32/bf16 storage) safe.
// ws layout (bytes):
//   [0)        int flag
//   [256)      gates: 384 f32
//   [4096)     meas: 4096*24 f32            (ends   397,312)
//   [397,312)  enc:  4096*256 f32           (ends 4,591,616)
//   [4,591,616)  P: 4M bf16 (h1,d2,d4)      (ends 12,980,224)
//   [12,980,224) Q: 2M bf16 (h2,d1,d3)      (ends 17,174,528)  ~16.4 MB

using bf16 = __hip_bfloat16;
typedef __attribute__((ext_vector_type(8))) short short8;
typedef __attribute__((ext_vector_type(4))) short short4v;
typedef __attribute__((ext_vector_type(4))) float f32x4;

__device__ inline float ldf(const float* p, size_t i) { return p[i]; }
__device__ inline float ldf(const bf16* p, size_t i) { return __bfloat162float(p[i]); }
__device__ inline void stf(float* p, size_t i, float v) { p[i] = v; }
__device__ inline void stf(bf16* p, size_t i, float v) { p[i] = __float2bfloat16(v); }

__device__ inline short f2bs(float x) {
  bf16 h = __float2bfloat16(x);
  return *reinterpret_cast<short*>(&h);
}

// load 8 consecutive elements as bf16 bit patterns
__device__ inline short8 ld8b(const bf16* p) { return *(const short8*)p; }
__device__ inline short8 ld8b(const float* p) {
  const float4 a = ((const float4*)p)[0];
  const float4 b = ((const float4*)p)[1];
  short8 r;
  r[0] = f2bs(a.x); r[1] = f2bs(a.y); r[2] = f2bs(a.z); r[3] = f2bs(a.w);
  r[4] = f2bs(b.x); r[5] = f2bs(b.y); r[6] = f2bs(b.z); r[7] = f2bs(b.w);
  return r;
}
// load 4 consecutive elements as bf16 bit patterns
__device__ inline short4v ld4b(const bf16* p) { return *(const short4v*)p; }
__device__ inline short4v ld4b(const float* p) {
  const float4 a = *(const float4*)p;
  short4v r;
  r[0] = f2bs(a.x); r[1] = f2bs(a.y); r[2] = f2bs(a.z); r[3] = f2bs(a.w);
  return r;
}

// ---------------- dtype probe on eb1 (1024 logical elems, uniform +-0.0198)
__global__ void probe_dtype(const unsigned short* __restrict__ bits,
                            int* __restrict__ flag) {
  __shared__ int s_big, s_evennz;
  if (threadIdx.x == 0) { s_big = 0; s_evennz = 0; }
  __syncthreads();
  int big = 0, evennz = 0;
  for (int t = threadIdx.x; t < 1024; t += 256) {
    unsigned int u = bits[t];
    float v = __uint_as_float(u << 16);
    float a = fabsf(v);
    if (!(a <= 1.0f)) big = 1;
    if ((t & 1) == 0 && (u & 0x7fffu) != 0) evennz = 1;
  }
  if (big) s_big = 1;
  if (evennz) s_evennz = 1;
  __syncthreads();
  if (threadIdx.x == 0) *flag = (!s_big && s_evennz) ? 1 : 0;  // 1 = bf16
}

// ---------------- MFMA GEMM: C = act(A @ W + bias). A:MxK, W:KxN row-major.
// 128x128 tile, BK=32, 256 threads (4 waves), each wave 64x64 via 4x4 MFMA
// 16x16x32_bf16 tiles. LDS: A as [m][k], B as [n][k], rows padded to 40.
template <typename TA, typename TW, typename TC, int ACT>
__global__ __launch_bounds__(256) void gemm_mfma(const int* __restrict__ flag, int want,
                                                 const TA* __restrict__ A,
                                                 const TW* __restrict__ W,
                                                 const TW* __restrict__ bias,
                                                 TC* __restrict__ C,
                                                 int M, int N, int K) {
  if (*flag != want) return;
  __shared__ __align__(16) short As[128 * 40];
  __shared__ __align__(16) short Bs[128 * 40];
  const int tid = threadIdx.x;
  const int lane = tid & 63;
  const int wave = tid >> 6;
  const int wm = wave >> 1, wn = wave & 1;
  const int bm = blockIdx.y * 128;
  const int bn = blockIdx.x * 128;

  // A staging coords: 2 chunks of 8 k-elems per thread
  const int a_row0 = tid >> 2;          // 0..63 (chunk adds +64)
  const int a_kcol = (tid & 3) << 3;    // 0,8,16,24
  // B staging coords: 4k x 4n per thread
  const int b_ncol = (tid & 31) << 2;   // 0..124
  const int b_krow = (tid >> 5) << 2;   // 0..28

  const int frag_m = lane & 15;
  const int frag_k = (lane >> 4) << 3;  // 0,8,16,24

  f32x4 acc[4][4] = {};

  for (int k0 = 0; k0 < K; k0 += 32) {
    // ---- stage A
#pragma unroll
    for (int c = 0; c < 2; ++c) {
      const int row = c * 64 + a_row0;
      short8 v;
      if (k0 + 32 <= K) {
        v = ld8b(A + (size_t)(bm + row) * K + k0 + a_kcol);
      } else {
#pragma unroll
        for (int j = 0; j < 8; ++j) {
          int k = k0 + a_kcol + j;
          v[j] = (k < K) ? f2bs(ldf(A, (size_t)(bm + row) * K + k)) : (short)0;
        }
      }
      *(short8*)&As[row * 40 + a_kcol] = v;
    }
    // ---- stage B (transpose to [n][k])
    short4v bv[4];
#pragma unroll
    for (int kk = 0; kk < 4; ++kk) {
      int k = k0 + b_krow + kk;
      if (k < K) bv[kk] = ld4b(W + (size_t)k * N + bn + b_ncol);
      else { bv[kk][0] = 0; bv[kk][1] = 0; bv[kk][2] = 0; bv[kk][3] = 0; }
    }
#pragma unroll
    for (int nn = 0; nn < 4; ++nn) {
      short4v w;
      w[0] = bv[0][nn]; w[1] = bv[1][nn]; w[2] = bv[2][nn]; w[3] = bv[3][nn];
      *(short4v*)&Bs[(b_ncol + nn) * 40 + b_krow] = w;
    }
    __syncthreads();

    // ---- fragments + MFMA
    short8 af[4], bf[4];
#pragma unroll
    for (int i = 0; i < 4; ++i)
      af[i] = *(const short8*)&As[(wm * 64 + i * 16 + frag_m) * 40 + frag_k];
#pragma unroll
    for (int j = 0; j < 4; ++j)
      bf[j] = *(const short8*)&Bs[(wn * 64 + j * 16 + frag_m) * 40 + frag_k];
#pragma unroll
    for (int i = 0; i < 4; ++i)
#pragma unroll
      for (int j = 0; j < 4; ++j)
        acc[i][j] = __builtin_amdgcn_mfma_f32_16x16x32_bf16(af[i], bf[j], acc[i][j], 0, 0, 0);
    __syncthreads();
  }

  // ---- epilogue: C/D layout col=lane&15, row=quad*4+reg
  const int col_lane = lane & 15;
  const int row_quad = (lane >> 4) << 2;
  float bj[4];
#pragma unroll
  for (int j = 0; j < 4; ++j)
    bj[j] = ldf(bias, (size_t)(bn + wn * 64 + j * 16 + col_lane));
#pragma unroll
  for (int i = 0; i < 4; ++i) {
#pragma unroll
    for (int j = 0; j < 4; ++j) {
      int n = bn + wn * 64 + j * 16 + col_lane;
#pragma unroll
      for (int r = 0; r < 4; ++r) {
        int m = bm + wm * 64 + i * 16 + row_quad + r;
        float v = acc[i][j][r] + bj[j];
        if (ACT == 0) v = (v >= 0.f) ? v : 0.2f * v;
        else v = tanhf(v);
        stf(C, (size_t)m * N + n, v);
      }
    }
  }
}

// ---------------- Gate precompute (48 Rot gates)
__global__ void prep_gates(const void* __restrict__ dp, const int* __restrict__ flag,
                           float* __restrict__ gw) {
  int g = threadIdx.x;
  if (g >= 48) return;
  float phi, theta, omega;
  if (*flag == 1) {
    const bf16* p = (const bf16*)dp;
    phi = __bfloat162float(p[g * 3 + 0]);
    theta = __bfloat162float(p[g * 3 + 1]);
    omega = __bfloat162float(p[g * 3 + 2]);
  } else {
    const float* p = (const float*)dp;
    phi = p[g * 3 + 0]; theta = p[g * 3 + 1]; omega = p[g * 3 + 2];
  }
  float c = cosf(0.5f * theta), s = sinf(0.5f * theta);
  float a = 0.5f * (phi + omega), d = 0.5f * (phi - omega);
  float ca = cosf(a), sa = sinf(a), cd = cosf(d), sd = sinf(d);
  float* o = gw + g * 8;
  o[0] =  ca * c; o[1] = -sa * c;
  o[2] = -cd * s; o[3] = -sd * s;
  o[4] =  cd * s; o[5] = -sd * s;
  o[6] =  ca * c; o[7] =  sa * c;
}

__device__ inline float wred(float v) {
#pragma unroll
  for (int o = 32; o > 0; o >>= 1) v += __shfl_down(v, o, 64);
  return v;
}

// ---------------- 8-qubit statevector circuit + Z/X/Y measurements
__global__ __launch_bounds__(256) void circuit_kernel(const float* __restrict__ enc,
                                                      const float* __restrict__ gw,
                                                      float* __restrict__ meas) {
  __shared__ float2 psi[256];
  __shared__ float gsh[384];
  __shared__ float wsum[4];
  __shared__ float partial[4][3];
  const int b = blockIdx.x;
  const int i = threadIdx.x;
  const int lane = i & 63, wid = i >> 6;

  for (int t = i; t < 384; t += 256) gsh[t] = gw[t];

  float v = enc[(size_t)b * 256 + i];
  float ss = wred(v * v);
  if (lane == 0) wsum[wid] = ss;
  __syncthreads();
  float nrm = sqrtf(wsum[0] + wsum[1] + wsum[2] + wsum[3]);
  nrm = fmaxf(nrm, 1e-12f);
  psi[i] = make_float2(v / nrm, 0.f);
  __syncthreads();

  for (int l = 0; l < 6; ++l) {
    for (int q = 0; q < 8; ++q) {
      const float* g = &gsh[(l * 8 + q) * 8];
      const int s = 1 << (7 - q);
      if (!(i & s)) {
        float2 p0 = psi[i], p1 = psi[i | s];
        float2 n0, n1;
        n0.x = g[0] * p0.x - g[1] * p0.y + g[2] * p1.x - g[3] * p1.y;
        n0.y = g[0] * p0.y + g[1] * p0.x + g[2] * p1.y + g[3] * p1.x;
        n1.x = g[4] * p0.x - g[5] * p0.y + g[6] * p1.x - g[7] * p1.y;
        n1.y = g[4] * p0.y + g[5] * p0.x + g[6] * p1.y + g[7] * p1.x;
        psi[i] = n0; psi[i | s] = n1;
      }
      __syncthreads();
    }
    const int r = l % 7 + 1;
    for (int q = 0; q < 8; ++q) {
      const int bc = 7 - q, bt = 7 - ((q + r) & 7);
      if (((i >> bc) & 1) && !((i >> bt) & 1)) {
        int j = i | (1 << bt);
        float2 tmp = psi[i]; psi[i] = psi[j]; psi[j] = tmp;
      }
      __syncthreads();
    }
  }

  float2 p = psi[i];
  float prob = p.x * p.x + p.y * p.y;
  for (int q = 0; q < 8; ++q) {
    const int s = 1 << (7 - q);
    float2 f = psi[i ^ s];
    float re = p.x * f.x + p.y * f.y;
    float im = p.x * f.y - p.y * f.x;
    float zc = wred((i & s) ? -prob : prob);
    float xc = wred(re);
    float yc = wred((i & s) ? -im : im);
    if (lane == 0) { partial[wid][0] = zc; partial[wid][1] = xc; partial[wid][2] = yc; }
    __syncthreads();
    if (i < 3) {
      meas[(size_t)b * 24 + i * 8 + q] =
          partial[0][i] + partial[1][i] + partial[2][i] + partial[3][i];
    }
    __syncthreads();
  }
}

extern "C" void kernel_launch(void* const* d_in, const int* in_sizes, int n_in,
                              void* d_out, int out_size, void* d_ws, size_t ws_size,
                              hipStream_t stream) {
  (void)in_sizes; (void)n_in; (void)out_size; (void)ws_size;
  char* wsb = (char*)d_ws;
  int*   flag = (int*)wsb;
  float* gw   = (float*)(wsb + 256);
  float* meas = (float*)(wsb + 4096);
  float* encf = (float*)(wsb + 397312);
  bf16*  P    = (bf16*)(wsb + 4591616);
  bf16*  Q    = (bf16*)(wsb + 12980224);

  probe_dtype<<<1, 256, 0, stream>>>((const unsigned short*)d_in[2], flag);
  prep_gates<<<1, 64, 0, stream>>>(d_in[7], flag, gw);

  // ---- encoder
  gemm_mfma<float, float, bf16, 0><<<dim3(8, 32), 256, 0, stream>>>(
      flag, 0, (const float*)d_in[0], (const float*)d_in[1], (const float*)d_in[2], P, 4096, 1024, 2560);
  gemm_mfma<bf16, bf16, bf16, 0><<<dim3(8, 32), 256, 0, stream>>>(
      flag, 1, (const bf16*)d_in[0], (const bf16*)d_in[1], (const bf16*)d_in[2], P, 4096, 1024, 2560);

  gemm_mfma<bf16, float, bf16, 0><<<dim3(4, 32), 256, 0, stream>>>(
      flag, 0, P, (const float*)d_in[3], (const float*)d_in[4], Q, 4096, 512, 1024);
  gemm_mfma<bf16, bf16, bf16, 0><<<dim3(4, 32), 256, 0, stream>>>(
      flag, 1, P, (const bf16*)d_in[3], (const bf16*)d_in[4], Q, 4096, 512, 1024);

  gemm_mfma<bf16, float, float, 1><<<dim3(2, 32), 256, 0, stream>>>(
      flag, 0, Q, (const float*)d_in[5], (const float*)d_in[6], encf, 4096, 256, 512);
  gemm_mfma<bf16, bf16, float, 1><<<dim3(2, 32), 256, 0, stream>>>(
      flag, 1, Q, (const bf16*)d_in[5], (const bf16*)d_in[6], encf, 4096, 256, 512);

  // ---- quantum circuit
  circuit_kernel<<<4096, 256, 0, stream>>>(encf, gw, meas);

  // ---- decoder
  gemm_mfma<float, float, bf16, 0><<<dim3(1, 32), 256, 0, stream>>>(
      flag, 0, meas, (const float*)d_in[8], (const float*)d_in[9], Q, 4096, 128, 24);
  gemm_mfma<float, bf16, bf16, 0><<<dim3(1, 32), 256, 0, stream>>>(
      flag, 1, meas, (const bf16*)d_in[8], (const bf16*)d_in[9], Q, 4096, 128, 24);

  gemm_mfma<bf16, float, bf16, 0><<<dim3(2, 32), 256, 0, stream>>>(
      flag, 0, Q, (const float*)d_in[10], (const float*)d_in[11], P, 4096, 256, 128);
  gemm_mfma<bf16, bf16, bf16, 0><<<dim3(2, 32), 256, 0, stream>>>(
      flag, 1, Q, (const bf16*)d_in[10], (const bf16*)d_in[11], P, 4096, 256, 128);

  gemm_mfma<bf16, float, bf16, 0><<<dim3(4, 32), 256, 0, stream>>>(
      flag, 0, P, (const float*)d_in[12], (const float*)d_in[13], Q, 4096, 512, 256);
  gemm_mfma<bf16, bf16, bf16, 0><<<dim3(4, 32), 256, 0, stream>>>(
      flag, 1, P, (const bf16*)d_in[12], (const bf16*)d_in[13], Q, 4096, 512, 256);

  gemm_mfma<bf16, float, bf16, 0><<<dim3(8, 32), 256, 0, stream>>>(
      flag, 0, Q, (const float*)d_in[14], (const float*)d_in[15], P, 4096, 1024, 512);
  gemm_mfma<bf16, bf16, bf16, 0><<<dim3(8, 32), 256, 0, stream>>>(
      flag, 1, Q, (const bf16*)d_in[14], (const bf16*)d_in[15], P, 4096, 1024, 512);

  gemm_mfma<bf16, float, float, 1><<<dim3(20, 32), 256, 0, stream>>>(
      flag, 0, P, (const float*)d_in[16], (const float*)d_in[17], (float*)d_out, 4096, 2560, 1024);
  gemm_mfma<bf16, bf16, bf16, 1><<<dim3(20, 32), 256, 0, stream>>>(
      flag, 1, P, (const bf16*)d_in[16], (const bf16*)d_in[17], (bf16*)d_out, 4096, 2560, 1024);
}

// Round 4
// 434.505 us; speedup vs baseline: 3.0875x; 1.6986x over previous
//
#include <hip/hip_runtime.h>
#include <hip/hip_bf16.h>

// Async-MFMA implementation, dual-dtype (f32/bf16 storage) safe.
// ws layout (bytes):
//   [0)          int flag
//   [256)        gates: 384 f32
//   [4096)       biasf: 6272 f32 (all 8 biases, offsets below)
//   [32768)      meas  bf16 [4096][32] (cols 24..31 zero)   ends   294,912
//   [294912)     encf  f32  [4096][256]                     ends 4,489,216
//   [4489216)    P     bf16 4096x1024 (h1,d2,d4)            ends 12,877,824
//   [12877824)   Q     bf16 4096x512  (h2,d1,d3)            ends 17,072,128
//   [17072128)   WT    bf16 transposed weights (13.18 MB)   ends 30,253,056

using bf16 = __hip_bfloat16;
typedef __attribute__((ext_vector_type(8))) short short8;
typedef __attribute__((ext_vector_type(4))) short short4v;
typedef __attribute__((ext_vector_type(4))) float f32x4;

__device__ inline float ldf(const float* p, size_t i) { return p[i]; }
__device__ inline float ldf(const bf16* p, size_t i) { return __bfloat162float(p[i]); }
__device__ inline void stf(float* p, size_t i, float v) { p[i] = v; }
__device__ inline void stf(bf16* p, size_t i, float v) { p[i] = __float2bfloat16(v); }

__device__ inline short f2bs(float x) {
  bf16 h = __float2bfloat16(x);
  return *reinterpret_cast<short*>(&h);
}
__device__ inline short8 ld8b(const bf16* p) { return *(const short8*)p; }
__device__ inline short8 ld8b(const float* p) {
  const float4 a = ((const float4*)p)[0];
  const float4 b = ((const float4*)p)[1];
  short8 r;
  r[0] = f2bs(a.x); r[1] = f2bs(a.y); r[2] = f2bs(a.z); r[3] = f2bs(a.w);
  r[4] = f2bs(b.x); r[5] = f2bs(b.y); r[6] = f2bs(b.z); r[7] = f2bs(b.w);
  return r;
}
__device__ inline short4v ld4b(const bf16* p) { return *(const short4v*)p; }
__device__ inline short4v ld4b(const float* p) {
  const float4 a = *(const float4*)p;
  short4v r;
  r[0] = f2bs(a.x); r[1] = f2bs(a.y); r[2] = f2bs(a.z); r[3] = f2bs(a.w);
  return r;
}

__device__ inline void async_load16(const bf16* g, short* l) {
  __builtin_amdgcn_global_load_lds(
      (const __attribute__((address_space(1))) unsigned int*)g,
      (__attribute__((address_space(3))) unsigned int*)l, 16, 0, 0);
}

// ---------------- dtype probe on eb1
__global__ void probe_dtype(const unsigned short* __restrict__ bits,
                            int* __restrict__ flag) {
  __shared__ int s_big, s_evennz;
  if (threadIdx.x == 0) { s_big = 0; s_evennz = 0; }
  __syncthreads();
  int big = 0, evennz = 0;
  for (int t = threadIdx.x; t < 1024; t += 256) {
    unsigned int u = bits[t];
    float v = __uint_as_float(u << 16);
    if (!(fabsf(v) <= 1.0f)) big = 1;
    if ((t & 1) == 0 && (u & 0x7fffu) != 0) evennz = 1;
  }
  if (big) s_big = 1;
  if (evennz) s_evennz = 1;
  __syncthreads();
  if (threadIdx.x == 0) *flag = (!s_big && s_evennz) ? 1 : 0;  // 1 = bf16
}

// ---------------- prep: transpose weights -> WT bf16 [N][Kp], biases -> f32, gates
__global__ __launch_bounds__(256) void prep_all(
    const int* __restrict__ flag,
    const void* w0, const void* w1, const void* w2, const void* w3,
    const void* w4, const void* w5, const void* w6, const void* w7,
    const void* b0, const void* b1, const void* b2, const void* b3,
    const void* b4, const void* b5, const void* b6, const void* b7,
    const void* dp,
    bf16* __restrict__ wt, float* __restrict__ biasf, float* __restrict__ gw) {
  const int isb = *flag;
  const int bid = blockIdx.x;
  const int tid = threadIdx.x;
  const int Ks[8]  = {2560, 1024, 512, 24, 128, 256, 512, 1024};
  const int Ns[8]  = {1024, 512, 256, 128, 256, 512, 1024, 2560};
  const int cum[8] = {2560, 3072, 3200, 3204, 3236, 3364, 3876, 6436};
  const long wto[8] = {0, 2621440, 3145728, 3276800, 3280896, 3313664, 3444736, 3969024};
  const void* Wp[8] = {w0, w1, w2, w3, w4, w5, w6, w7};
  const void* Bp[8] = {b0, b1, b2, b3, b4, b5, b6, b7};
  const int boff[8] = {0, 1024, 1536, 1792, 1920, 2176, 2688, 3712};

  if (bid < 6436) {
    int t = 0;
    while (bid >= cum[t]) t++;
    int base = t ? cum[t - 1] : 0;
    int local = bid - base;
    int K = Ks[t], N = Ns[t];
    int tk = (K + 31) >> 5;
    int kt = local % tk, nt = local / tk;
    int Kp = tk << 5;
    __shared__ short tile[32][33];
    int r = tid >> 3, c4 = (tid & 7) << 2;
    int gk = kt * 32 + r, gn = nt * 32 + c4;
    short4v v;
    if (gk < K) {
      if (isb) v = ld4b((const bf16*)Wp[t] + (size_t)gk * N + gn);
      else     v = ld4b((const float*)Wp[t] + (size_t)gk * N + gn);
    } else { v[0] = 0; v[1] = 0; v[2] = 0; v[3] = 0; }
    tile[r][c4] = v[0]; tile[r][c4 + 1] = v[1]; tile[r][c4 + 2] = v[2]; tile[r][c4 + 3] = v[3];
    __syncthreads();
    int n = tid >> 3, k4 = (tid & 7) << 2;
    short4v o;
    o[0] = tile[k4][n]; o[1] = tile[k4 + 1][n]; o[2] = tile[k4 + 2][n]; o[3] = tile[k4 + 3][n];
    *(short4v*)&wt[wto[t] + (size_t)(nt * 32 + n) * Kp + kt * 32 + k4] = o;
  } else if (bid < 6444) {
    int b = bid - 6436;
    int nb = Ns[b];  // bias length == N of layer b
    for (int t2 = tid; t2 < nb; t2 += 256) {
      float val = isb ? __bfloat162float(((const bf16*)Bp[b])[t2])
                      : ((const float*)Bp[b])[t2];
      biasf[boff[b] + t2] = val;
    }
  } else {
    int g = tid;
    if (g < 48) {
      float phi, theta, omega;
      if (isb) {
        const bf16* p = (const bf16*)dp;
        phi = __bfloat162float(p[g * 3 + 0]);
        theta = __bfloat162float(p[g * 3 + 1]);
        omega = __bfloat162float(p[g * 3 + 2]);
      } else {
        const float* p = (const float*)dp;
        phi = p[g * 3 + 0]; theta = p[g * 3 + 1]; omega = p[g * 3 + 2];
      }
      float c = cosf(0.5f * theta), s = sinf(0.5f * theta);
      float a = 0.5f * (phi + omega), d = 0.5f * (phi - omega);
      float ca = cosf(a), sa = sinf(a), cd = cosf(d), sd = sinf(d);
      float* o = gw + g * 8;
      o[0] =  ca * c; o[1] = -sa * c;
      o[2] = -cd * s; o[3] = -sd * s;
      o[4] =  cd * s; o[5] = -sd * s;
      o[6] =  ca * c; o[7] =  sa * c;
    }
  }
}

// ---------------- async MFMA GEMM: C = act(A @ Bt^T + bias)
// A: [M][K] bf16 (rows 64B-mult), Bt: [N][K] bf16. BK=32.
// global_load_lds staging (unpadded LDS, wave-uniform base + lane*16).
template <int BM, int BN, int WR, int WC, int ACT, typename TC>
__global__ __launch_bounds__(256) void gemm_async(const int* __restrict__ flag, int want,
                                                  const bf16* __restrict__ A,
                                                  const bf16* __restrict__ Bt,
                                                  const float* __restrict__ bias,
                                                  TC* __restrict__ C,
                                                  int M, int N, int K) {
  if (want >= 0 && *flag != want) return;
  constexpr int WMT = BM / WR;
  constexpr int WNT = BN / WC;
  constexpr int FI = WMT / 16;
  constexpr int FJ = WNT / 16;
  __shared__ __align__(16) short As[BM * 32];
  __shared__ __align__(16) short Bs[BN * 32];
  const int tid = threadIdx.x;
  const int lane = tid & 63;
  const int wid = tid >> 6;
  const int wm = wid / WC, wn = wid % WC;
  const int bm = blockIdx.y * BM;
  const int bn = blockIdx.x * BN;

  const int st_row = wid * 16 + (lane >> 2);  // row within 64-row group
  const int st_col = (lane & 3) * 8;          // element offset (16B chunk)

  const int frag_m = lane & 15;
  const int frag_k = (lane >> 4) * 8;

  f32x4 acc[FI][FJ] = {};

  for (int k0 = 0; k0 < K; k0 += 32) {
#pragma unroll
    for (int c = 0; c < BM / 64; ++c) {
      const bf16* g = A + (size_t)(bm + c * 64 + st_row) * K + k0 + st_col;
      async_load16(g, &As[(c * 64 + wid * 16) * 32]);
    }
#pragma unroll
    for (int c = 0; c < BN / 64; ++c) {
      const bf16* g = Bt + (size_t)(bn + c * 64 + st_row) * K + k0 + st_col;
      async_load16(g, &Bs[(c * 64 + wid * 16) * 32]);
    }
    __syncthreads();
    short8 af[FI], bfr[FJ];
#pragma unroll
    for (int i = 0; i < FI; ++i)
      af[i] = *(const short8*)&As[(wm * WMT + i * 16 + frag_m) * 32 + frag_k];
#pragma unroll
    for (int j = 0; j < FJ; ++j)
      bfr[j] = *(const short8*)&Bs[(wn * WNT + j * 16 + frag_m) * 32 + frag_k];
#pragma unroll
    for (int i = 0; i < FI; ++i)
#pragma unroll
      for (int j = 0; j < FJ; ++j)
        acc[i][j] = __builtin_amdgcn_mfma_f32_16x16x32_bf16(af[i], bfr[j], acc[i][j], 0, 0, 0);
    __syncthreads();
  }

  const int col_lane = lane & 15;
  const int row_quad = (lane >> 4) << 2;
#pragma unroll
  for (int i = 0; i < FI; ++i) {
#pragma unroll
    for (int j = 0; j < FJ; ++j) {
      int n = bn + wn * WNT + j * 16 + col_lane;
      float bj = bias[n];
#pragma unroll
      for (int r = 0; r < 4; ++r) {
        int m = bm + wm * WMT + i * 16 + row_quad + r;
        float v = acc[i][j][r] + bj;
        if (ACT == 0) v = (v >= 0.f) ? v : 0.2f * v;
        else v = tanhf(v);
        stf(C, (size_t)m * N + n, v);
      }
    }
  }
}

// ---------------- fallback GEMM1 for f32 storage (round-3 structure, proven)
__global__ __launch_bounds__(256) void gemm_cvt(const int* __restrict__ flag,
                                                const float* __restrict__ A,
                                                const float* __restrict__ W,
                                                const float* __restrict__ bias,
                                                bf16* __restrict__ C,
                                                int M, int N, int K) {
  if (*flag != 0) return;
  __shared__ __align__(16) short As[128 * 40];
  __shared__ __align__(16) short Bs[128 * 40];
  const int tid = threadIdx.x;
  const int lane = tid & 63;
  const int wave = tid >> 6;
  const int wm = wave >> 1, wn = wave & 1;
  const int bm = blockIdx.y * 128;
  const int bn = blockIdx.x * 128;
  const int a_row0 = tid >> 2;
  const int a_kcol = (tid & 3) << 3;
  const int b_ncol = (tid & 31) << 2;
  const int b_krow = (tid >> 5) << 2;
  const int frag_m = lane & 15;
  const int frag_k = (lane >> 4) << 3;

  f32x4 acc[4][4] = {};

  for (int k0 = 0; k0 < K; k0 += 32) {
#pragma unroll
    for (int c = 0; c < 2; ++c) {
      const int row = c * 64 + a_row0;
      short8 v = ld8b(A + (size_t)(bm + row) * K + k0 + a_kcol);
      *(short8*)&As[row * 40 + a_kcol] = v;
    }
    short4v bv[4];
#pragma unroll
    for (int kk = 0; kk < 4; ++kk)
      bv[kk] = ld4b(W + (size_t)(k0 + b_krow + kk) * N + bn + b_ncol);
#pragma unroll
    for (int nn = 0; nn < 4; ++nn) {
      short4v w;
      w[0] = bv[0][nn]; w[1] = bv[1][nn]; w[2] = bv[2][nn]; w[3] = bv[3][nn];
      *(short4v*)&Bs[(b_ncol + nn) * 40 + b_krow] = w;
    }
    __syncthreads();
    short8 af[4], bfr[4];
#pragma unroll
    for (int i = 0; i < 4; ++i)
      af[i] = *(const short8*)&As[(wm * 64 + i * 16 + frag_m) * 40 + frag_k];
#pragma unroll
    for (int j = 0; j < 4; ++j)
      bfr[j] = *(const short8*)&Bs[(wn * 64 + j * 16 + frag_m) * 40 + frag_k];
#pragma unroll
    for (int i = 0; i < 4; ++i)
#pragma unroll
      for (int j = 0; j < 4; ++j)
        acc[i][j] = __builtin_amdgcn_mfma_f32_16x16x32_bf16(af[i], bfr[j], acc[i][j], 0, 0, 0);
    __syncthreads();
  }

  const int col_lane = lane & 15;
  const int row_quad = (lane >> 4) << 2;
#pragma unroll
  for (int i = 0; i < 4; ++i)
#pragma unroll
    for (int j = 0; j < 4; ++j) {
      int n = bn + wn * 64 + j * 16 + col_lane;
      float bj = bias[n];
#pragma unroll
      for (int r = 0; r < 4; ++r) {
        int m = bm + wm * 64 + i * 16 + row_quad + r;
        float v = acc[i][j][r] + bj;
        v = (v >= 0.f) ? v : 0.2f * v;
        stf(C, (size_t)m * N + n, v);
      }
    }
}

__device__ inline float wred(float v) {
#pragma unroll
  for (int o = 32; o > 0; o >>= 1) v += __shfl_down(v, o, 64);
  return v;
}

// ---------------- 8-qubit statevector circuit + Z/X/Y measurements
__global__ __launch_bounds__(256) void circuit_kernel(const float* __restrict__ enc,
                                                      const float* __restrict__ gw,
                                                      bf16* __restrict__ meas) {
  __shared__ float2 psi[256];
  __shared__ float gsh[384];
  __shared__ float wsum[4];
  __shared__ float partial[4][3];
  const int b = blockIdx.x;
  const int i = threadIdx.x;
  const int lane = i & 63, wid = i >> 6;

  for (int t = i; t < 384; t += 256) gsh[t] = gw[t];
  if (i < 8) meas[(size_t)b * 32 + 24 + i] = __float2bfloat16(0.f);

  float v = enc[(size_t)b * 256 + i];
  float ss = wred(v * v);
  if (lane == 0) wsum[wid] = ss;
  __syncthreads();
  float nrm = sqrtf(wsum[0] + wsum[1] + wsum[2] + wsum[3]);
  nrm = fmaxf(nrm, 1e-12f);
  psi[i] = make_float2(v / nrm, 0.f);
  __syncthreads();

  for (int l = 0; l < 6; ++l) {
    for (int q = 0; q < 8; ++q) {
      const float* g = &gsh[(l * 8 + q) * 8];
      const int s = 1 << (7 - q);
      if (!(i & s)) {
        float2 p0 = psi[i], p1 = psi[i | s];
        float2 n0, n1;
        n0.x = g[0] * p0.x - g[1] * p0.y + g[2] * p1.x - g[3] * p1.y;
        n0.y = g[0] * p0.y + g[1] * p0.x + g[2] * p1.y + g[3] * p1.x;
        n1.x = g[4] * p0.x - g[5] * p0.y + g[6] * p1.x - g[7] * p1.y;
        n1.y = g[4] * p0.y + g[5] * p0.x + g[6] * p1.y + g[7] * p1.x;
        psi[i] = n0; psi[i | s] = n1;
      }
      __syncthreads();
    }
    const int r = l % 7 + 1;
    for (int q = 0; q < 8; ++q) {
      const int bc = 7 - q, bt = 7 - ((q + r) & 7);
      if (((i >> bc) & 1) && !((i >> bt) & 1)) {
        int j = i | (1 << bt);
        float2 tmp = psi[i]; psi[i] = psi[j]; psi[j] = tmp;
      }
      __syncthreads();
    }
  }

  float2 p = psi[i];
  float prob = p.x * p.x + p.y * p.y;
  for (int q = 0; q < 8; ++q) {
    const int s = 1 << (7 - q);
    float2 f = psi[i ^ s];
    float re = p.x * f.x + p.y * f.y;
    float im = p.x * f.y - p.y * f.x;
    float zc = wred((i & s) ? -prob : prob);
    float xc = wred(re);
    float yc = wred((i & s) ? -im : im);
    if (lane == 0) { partial[wid][0] = zc; partial[wid][1] = xc; partial[wid][2] = yc; }
    __syncthreads();
    if (i < 3) {
      meas[(size_t)b * 32 + i * 8 + q] = __float2bfloat16(
          partial[0][i] + partial[1][i] + partial[2][i] + partial[3][i]);
    }
    __syncthreads();
  }
}

extern "C" void kernel_launch(void* const* d_in, const int* in_sizes, int n_in,
                              void* d_out, int out_size, void* d_ws, size_t ws_size,
                              hipStream_t stream) {
  (void)in_sizes; (void)n_in; (void)out_size; (void)ws_size;
  char* wsb = (char*)d_ws;
  int*   flag  = (int*)wsb;
  float* gw    = (float*)(wsb + 256);
  float* biasf = (float*)(wsb + 4096);
  bf16*  meas  = (bf16*)(wsb + 32768);
  float* encf  = (float*)(wsb + 294912);
  bf16*  P     = (bf16*)(wsb + 4489216);
  bf16*  Q     = (bf16*)(wsb + 12877824);
  bf16*  WT    = (bf16*)(wsb + 17072128);

  // transposed-weight offsets (bf16 elems)
  bf16* ew1t = WT + 0;
  bf16* ew2t = WT + 2621440;
  bf16* ew3t = WT + 3145728;
  bf16* dw1t = WT + 3276800;
  bf16* dw2t = WT + 3280896;
  bf16* dw3t = WT + 3313664;
  bf16* dw4t = WT + 3444736;
  bf16* dw5t = WT + 3969024;
  // bias f32 offsets
  float* beb1 = biasf + 0;
  float* beb2 = biasf + 1024;
  float* beb3 = biasf + 1536;
  float* bdb1 = biasf + 1792;
  float* bdb2 = biasf + 1920;
  float* bdb3 = biasf + 2176;
  float* bdb4 = biasf + 2688;
  float* bdb5 = biasf + 3712;

  probe_dtype<<<1, 256, 0, stream>>>((const unsigned short*)d_in[2], flag);
  prep_all<<<6445, 256, 0, stream>>>(flag,
      d_in[1], d_in[3], d_in[5], d_in[8], d_in[10], d_in[12], d_in[14], d_in[16],
      d_in[2], d_in[4], d_in[6], d_in[9], d_in[11], d_in[13], d_in[15], d_in[17],
      d_in[7], WT, biasf, gw);

  // ---- GEMM1: h1 = leaky(x @ ew1 + eb1)   [4096x1024, K=2560]
  gemm_async<128, 64, 4, 1, 0, bf16><<<dim3(16, 32), 256, 0, stream>>>(
      flag, 1, (const bf16*)d_in[0], ew1t, beb1, P, 4096, 1024, 2560);
  gemm_cvt<<<dim3(8, 32), 256, 0, stream>>>(
      flag, (const float*)d_in[0], (const float*)d_in[1], (const float*)d_in[2], P,
      4096, 1024, 2560);

  // ---- GEMM2: h2 = leaky(h1 @ ew2 + eb2)  [4096x512, K=1024]
  gemm_async<64, 64, 2, 2, 0, bf16><<<dim3(8, 64), 256, 0, stream>>>(
      flag, -1, P, ew2t, beb2, Q, 4096, 512, 1024);
  // ---- GEMM3: enc = tanh(h2 @ ew3 + eb3)  [4096x256, K=512] -> f32
  gemm_async<64, 64, 2, 2, 1, float><<<dim3(4, 64), 256, 0, stream>>>(
      flag, -1, Q, ew3t, beb3, encf, 4096, 256, 512);

  // ---- quantum circuit -> meas bf16 [4096][32] (24 used)
  circuit_kernel<<<4096, 256, 0, stream>>>(encf, gw, meas);

  // ---- decoder
  gemm_async<64, 64, 2, 2, 0, bf16><<<dim3(2, 64), 256, 0, stream>>>(
      flag, -1, meas, dw1t, bdb1, Q, 4096, 128, 32);
  gemm_async<64, 64, 2, 2, 0, bf16><<<dim3(4, 64), 256, 0, stream>>>(
      flag, -1, Q, dw2t, bdb2, P, 4096, 256, 128);
  gemm_async<64, 64, 2, 2, 0, bf16><<<dim3(8, 64), 256, 0, stream>>>(
      flag, -1, P, dw3t, bdb3, Q, 4096, 512, 256);
  gemm_async<128, 64, 4, 1, 0, bf16><<<dim3(16, 32), 256, 0, stream>>>(
      flag, -1, Q, dw4t, bdb4, P, 4096, 1024, 512);
  // ---- GEMM d5: out = tanh(d4 @ dw5 + db5)  [4096x2560, K=1024], dual output dtype
  gemm_async<128, 128, 2, 2, 1, bf16><<<dim3(20, 32), 256, 0, stream>>>(
      flag, 1, P, dw5t, bdb5, (bf16*)d_out, 4096, 2560, 1024);
  gemm_async<128, 128, 2, 2, 1, float><<<dim3(20, 32), 256, 0, stream>>>(
      flag, 0, P, dw5t, bdb5, (float*)d_out, 4096, 2560, 1024);
}

// Round 5
// 367.417 us; speedup vs baseline: 3.6513x; 1.1826x over previous
//
#include <hip/hip_runtime.h>
#include <hip/hip_bf16.h>

// f32-storage-committed implementation (proven by round-4 counters:
// gemm_cvt [flag==0-gated] did real work; f32-output d5 passed).
// ws layout (bytes):
//   [256)        gates: 384 f32
//   [4096)       biasf: 6272 f32
//   [32768)      meas  bf16 [4096][32] (cols 24..31 zero)   ends   294,912
//   [294912)     encf  f32  [4096][256]                     ends 4,489,216
//   [4489216)    P     bf16 4096x1024 (h1,d2,d4)            ends 12,877,824
//   [12877824)   Q     bf16 4096x512  (h2,d1,d3)            ends 17,072,128
//   [17072128)   WT    bf16 transposed weights (13.18 MB)   ends 30,253,056
//   [30253056)   Xb    bf16 4096x2560 (x converted)         ends 51,224,576

using bf16 = __hip_bfloat16;
typedef __attribute__((ext_vector_type(8))) short short8;
typedef __attribute__((ext_vector_type(4))) short short4v;
typedef __attribute__((ext_vector_type(4))) float f32x4;

__device__ inline void stf(float* p, size_t i, float v) { p[i] = v; }
__device__ inline void stf(bf16* p, size_t i, float v) { p[i] = __float2bfloat16(v); }

__device__ inline short f2bs(float x) {
  bf16 h = __float2bfloat16(x);
  return *reinterpret_cast<short*>(&h);
}
__device__ inline short8 ld8b(const float* p) {
  const float4 a = ((const float4*)p)[0];
  const float4 b = ((const float4*)p)[1];
  short8 r;
  r[0] = f2bs(a.x); r[1] = f2bs(a.y); r[2] = f2bs(a.z); r[3] = f2bs(a.w);
  r[4] = f2bs(b.x); r[5] = f2bs(b.y); r[6] = f2bs(b.z); r[7] = f2bs(b.w);
  return r;
}
__device__ inline short4v ld4b(const float* p) {
  const float4 a = *(const float4*)p;
  short4v r;
  r[0] = f2bs(a.x); r[1] = f2bs(a.y); r[2] = f2bs(a.z); r[3] = f2bs(a.w);
  return r;
}

__device__ inline void async_load16(const bf16* g, short* l) {
  __builtin_amdgcn_global_load_lds(
      (const __attribute__((address_space(1))) unsigned int*)g,
      (__attribute__((address_space(3))) unsigned int*)l, 16, 0, 0);
}

// ---------------- x f32 -> bf16 bulk convert
__global__ __launch_bounds__(256) void cvt_f32_bf16(const float* __restrict__ in,
                                                    bf16* __restrict__ out, long n) {
  long i = ((long)blockIdx.x * 256 + threadIdx.x) * 8;
  if (i >= n) return;
  short8 v = ld8b(in + i);
  *(short8*)((short*)out + i) = v;
}

// ---------------- prep: transpose weights -> WT bf16 [N][Kp], biases, gates
__global__ __launch_bounds__(256) void prep_all(
    const float* w0, const float* w1, const float* w2, const float* w3,
    const float* w4, const float* w5, const float* w6, const float* w7,
    const float* b0, const float* b1, const float* b2, const float* b3,
    const float* b4, const float* b5, const float* b6, const float* b7,
    const float* dp,
    bf16* __restrict__ wt, float* __restrict__ biasf, float* __restrict__ gw) {
  const int bid = blockIdx.x;
  const int tid = threadIdx.x;
  const int Ks[8]  = {2560, 1024, 512, 24, 128, 256, 512, 1024};
  const int Ns[8]  = {1024, 512, 256, 128, 256, 512, 1024, 2560};
  const int cum[8] = {2560, 3072, 3200, 3204, 3236, 3364, 3876, 6436};
  const long wto[8] = {0, 2621440, 3145728, 3276800, 3280896, 3313664, 3444736, 3969024};
  const float* Wp[8] = {w0, w1, w2, w3, w4, w5, w6, w7};
  const float* Bp[8] = {b0, b1, b2, b3, b4, b5, b6, b7};
  const int boff[8] = {0, 1024, 1536, 1792, 1920, 2176, 2688, 3712};

  if (bid < 6436) {
    int t = 0;
    while (bid >= cum[t]) t++;
    int base = t ? cum[t - 1] : 0;
    int local = bid - base;
    int K = Ks[t], N = Ns[t];
    int tk = (K + 31) >> 5;
    int kt = local % tk, nt = local / tk;
    int Kp = tk << 5;
    __shared__ short tile[32][33];
    int r = tid >> 3, c4 = (tid & 7) << 2;
    int gk = kt * 32 + r, gn = nt * 32 + c4;
    short4v v;
    if (gk < K) v = ld4b(Wp[t] + (size_t)gk * N + gn);
    else { v[0] = 0; v[1] = 0; v[2] = 0; v[3] = 0; }
    tile[r][c4] = v[0]; tile[r][c4 + 1] = v[1]; tile[r][c4 + 2] = v[2]; tile[r][c4 + 3] = v[3];
    __syncthreads();
    int n = tid >> 3, k4 = (tid & 7) << 2;
    short4v o;
    o[0] = tile[k4][n]; o[1] = tile[k4 + 1][n]; o[2] = tile[k4 + 2][n]; o[3] = tile[k4 + 3][n];
    *(short4v*)&wt[wto[t] + (size_t)(nt * 32 + n) * Kp + kt * 32 + k4] = o;
  } else if (bid < 6444) {
    int b = bid - 6436;
    int nb = Ns[b];
    for (int t2 = tid; t2 < nb; t2 += 256)
      biasf[boff[b] + t2] = Bp[b][t2];
  } else {
    int g = tid;
    if (g < 48) {
      float phi = dp[g * 3 + 0], theta = dp[g * 3 + 1], omega = dp[g * 3 + 2];
      float c = cosf(0.5f * theta), s = sinf(0.5f * theta);
      float a = 0.5f * (phi + omega), d = 0.5f * (phi - omega);
      float ca = cosf(a), sa = sinf(a), cd = cosf(d), sd = sinf(d);
      float* o = gw + g * 8;
      o[0] =  ca * c; o[1] = -sa * c;
      o[2] = -cd * s; o[3] = -sd * s;
      o[4] =  cd * s; o[5] = -sd * s;
      o[6] =  ca * c; o[7] =  sa * c;
    }
  }
}

// ---------------- async MFMA GEMM: C = act(A @ Bt^T + bias)
// A: [M][K] bf16, Bt: [N][K] bf16, BK=32, global_load_lds staging.
template <int BM, int BN, int WR, int WC, int ACT, typename TC>
__global__ __launch_bounds__(256) void gemm_async(const bf16* __restrict__ A,
                                                  const bf16* __restrict__ Bt,
                                                  const float* __restrict__ bias,
                                                  TC* __restrict__ C,
                                                  int M, int N, int K) {
  constexpr int WMT = BM / WR;
  constexpr int WNT = BN / WC;
  constexpr int FI = WMT / 16;
  constexpr int FJ = WNT / 16;
  __shared__ __align__(16) short As[BM * 32];
  __shared__ __align__(16) short Bs[BN * 32];
  const int tid = threadIdx.x;
  const int lane = tid & 63;
  const int wid = tid >> 6;
  const int wm = wid / WC, wn = wid % WC;
  const int bm = blockIdx.y * BM;
  const int bn = blockIdx.x * BN;

  const int st_row = wid * 16 + (lane >> 2);
  const int st_col = (lane & 3) * 8;

  const int frag_m = lane & 15;
  const int frag_k = (lane >> 4) * 8;

  f32x4 acc[FI][FJ] = {};

  for (int k0 = 0; k0 < K; k0 += 32) {
#pragma unroll
    for (int c = 0; c < BM / 64; ++c) {
      const bf16* g = A + (size_t)(bm + c * 64 + st_row) * K + k0 + st_col;
      async_load16(g, &As[(c * 64 + wid * 16) * 32]);
    }
#pragma unroll
    for (int c = 0; c < BN / 64; ++c) {
      const bf16* g = Bt + (size_t)(bn + c * 64 + st_row) * K + k0 + st_col;
      async_load16(g, &Bs[(c * 64 + wid * 16) * 32]);
    }
    __syncthreads();
    short8 af[FI], bfr[FJ];
#pragma unroll
    for (int i = 0; i < FI; ++i)
      af[i] = *(const short8*)&As[(wm * WMT + i * 16 + frag_m) * 32 + frag_k];
#pragma unroll
    for (int j = 0; j < FJ; ++j)
      bfr[j] = *(const short8*)&Bs[(wn * WNT + j * 16 + frag_m) * 32 + frag_k];
#pragma unroll
    for (int i = 0; i < FI; ++i)
#pragma unroll
      for (int j = 0; j < FJ; ++j)
        acc[i][j] = __builtin_amdgcn_mfma_f32_16x16x32_bf16(af[i], bfr[j], acc[i][j], 0, 0, 0);
    __syncthreads();
  }

  const int col_lane = lane & 15;
  const int row_quad = (lane >> 4) << 2;
#pragma unroll
  for (int i = 0; i < FI; ++i) {
#pragma unroll
    for (int j = 0; j < FJ; ++j) {
      int n = bn + wn * WNT + j * 16 + col_lane;
      float bj = bias[n];
#pragma unroll
      for (int r = 0; r < 4; ++r) {
        int m = bm + wm * WMT + i * 16 + row_quad + r;
        float v = acc[i][j][r] + bj;
        if (ACT == 0) v = (v >= 0.f) ? v : 0.2f * v;
        else v = tanhf(v);
        stf(C, (size_t)m * N + n, v);
      }
    }
  }
}

// ---------------- fallback GEMM1 (f32 A and W, converts in-kernel) — only
// used when ws_size is too small for the Xb buffer.
__global__ __launch_bounds__(256) void gemm_cvt(const float* __restrict__ A,
                                                const float* __restrict__ W,
                                                const float* __restrict__ bias,
                                                bf16* __restrict__ C,
                                                int M, int N, int K) {
  __shared__ __align__(16) short As[128 * 40];
  __shared__ __align__(16) short Bs[128 * 40];
  const int tid = threadIdx.x;
  const int lane = tid & 63;
  const int wave = tid >> 6;
  const int wm = wave >> 1, wn = wave & 1;
  const int bm = blockIdx.y * 128;
  const int bn = blockIdx.x * 128;
  const int a_row0 = tid >> 2;
  const int a_kcol = (tid & 3) << 3;
  const int b_ncol = (tid & 31) << 2;
  const int b_krow = (tid >> 5) << 2;
  const int frag_m = lane & 15;
  const int frag_k = (lane >> 4) << 3;

  f32x4 acc[4][4] = {};

  for (int k0 = 0; k0 < K; k0 += 32) {
#pragma unroll
    for (int c = 0; c < 2; ++c) {
      const int row = c * 64 + a_row0;
      short8 v = ld8b(A + (size_t)(bm + row) * K + k0 + a_kcol);
      *(short8*)&As[row * 40 + a_kcol] = v;
    }
    short4v bv[4];
#pragma unroll
    for (int kk = 0; kk < 4; ++kk)
      bv[kk] = ld4b(W + (size_t)(k0 + b_krow + kk) * N + bn + b_ncol);
#pragma unroll
    for (int nn = 0; nn < 4; ++nn) {
      short4v w;
      w[0] = bv[0][nn]; w[1] = bv[1][nn]; w[2] = bv[2][nn]; w[3] = bv[3][nn];
      *(short4v*)&Bs[(b_ncol + nn) * 40 + b_krow] = w;
    }
    __syncthreads();
    short8 af[4], bfr[4];
#pragma unroll
    for (int i = 0; i < 4; ++i)
      af[i] = *(const short8*)&As[(wm * 64 + i * 16 + frag_m) * 40 + frag_k];
#pragma unroll
    for (int j = 0; j < 4; ++j)
      bfr[j] = *(const short8*)&Bs[(wn * 64 + j * 16 + frag_m) * 40 + frag_k];
#pragma unroll
    for (int i = 0; i < 4; ++i)
#pragma unroll
      for (int j = 0; j < 4; ++j)
        acc[i][j] = __builtin_amdgcn_mfma_f32_16x16x32_bf16(af[i], bfr[j], acc[i][j], 0, 0, 0);
    __syncthreads();
  }

  const int col_lane = lane & 15;
  const int row_quad = (lane >> 4) << 2;
#pragma unroll
  for (int i = 0; i < 4; ++i)
#pragma unroll
    for (int j = 0; j < 4; ++j) {
      int n = bn + wn * 64 + j * 16 + col_lane;
      float bj = bias[n];
#pragma unroll
      for (int r = 0; r < 4; ++r) {
        int m = bm + wm * 64 + i * 16 + row_quad + r;
        float v = acc[i][j][r] + bj;
        v = (v >= 0.f) ? v : 0.2f * v;
        stf(C, (size_t)m * N + n, v);
      }
    }
}

__device__ inline float wred(float v) {
#pragma unroll
  for (int o = 32; o > 0; o >>= 1) v += __shfl_down(v, o, 64);
  return v;
}

// ---------------- 8-qubit statevector circuit + Z/X/Y measurements
__global__ __launch_bounds__(256) void circuit_kernel(const float* __restrict__ enc,
                                                      const float* __restrict__ gw,
                                                      bf16* __restrict__ meas) {
  __shared__ float2 psi[256];
  __shared__ float gsh[384];
  __shared__ float wsum[4];
  __shared__ float partial[4][3];
  const int b = blockIdx.x;
  const int i = threadIdx.x;
  const int lane = i & 63, wid = i >> 6;

  for (int t = i; t < 384; t += 256) gsh[t] = gw[t];
  if (i < 8) meas[(size_t)b * 32 + 24 + i] = __float2bfloat16(0.f);

  float v = enc[(size_t)b * 256 + i];
  float ss = wred(v * v);
  if (lane == 0) wsum[wid] = ss;
  __syncthreads();
  float nrm = sqrtf(wsum[0] + wsum[1] + wsum[2] + wsum[3]);
  nrm = fmaxf(nrm, 1e-12f);
  psi[i] = make_float2(v / nrm, 0.f);
  __syncthreads();

  for (int l = 0; l < 6; ++l) {
    for (int q = 0; q < 8; ++q) {
      const float* g = &gsh[(l * 8 + q) * 8];
      const int s = 1 << (7 - q);
      if (!(i & s)) {
        float2 p0 = psi[i], p1 = psi[i | s];
        float2 n0, n1;
        n0.x = g[0] * p0.x - g[1] * p0.y + g[2] * p1.x - g[3] * p1.y;
        n0.y = g[0] * p0.y + g[1] * p0.x + g[2] * p1.y + g[3] * p1.x;
        n1.x = g[4] * p0.x - g[5] * p0.y + g[6] * p1.x - g[7] * p1.y;
        n1.y = g[4] * p0.y + g[5] * p0.x + g[6] * p1.y + g[7] * p1.x;
        psi[i] = n0; psi[i | s] = n1;
      }
      __syncthreads();
    }
    const int r = l % 7 + 1;
    for (int q = 0; q < 8; ++q) {
      const int bc = 7 - q, bt = 7 - ((q + r) & 7);
      if (((i >> bc) & 1) && !((i >> bt) & 1)) {
        int j = i | (1 << bt);
        float2 tmp = psi[i]; psi[i] = psi[j]; psi[j] = tmp;
      }
      __syncthreads();
    }
  }

  float2 p = psi[i];
  float prob = p.x * p.x + p.y * p.y;
  for (int q = 0; q < 8; ++q) {
    const int s = 1 << (7 - q);
    float2 f = psi[i ^ s];
    float re = p.x * f.x + p.y * f.y;
    float im = p.x * f.y - p.y * f.x;
    float zc = wred((i & s) ? -prob : prob);
    float xc = wred(re);
    float yc = wred((i & s) ? -im : im);
    if (lane == 0) { partial[wid][0] = zc; partial[wid][1] = xc; partial[wid][2] = yc; }
    __syncthreads();
    if (i < 3) {
      meas[(size_t)b * 32 + i * 8 + q] = __float2bfloat16(
          partial[0][i] + partial[1][i] + partial[2][i] + partial[3][i]);
    }
    __syncthreads();
  }
}

extern "C" void kernel_launch(void* const* d_in, const int* in_sizes, int n_in,
                              void* d_out, int out_size, void* d_ws, size_t ws_size,
                              hipStream_t stream) {
  (void)in_sizes; (void)n_in; (void)out_size;
  char* wsb = (char*)d_ws;
  float* gw    = (float*)(wsb + 256);
  float* biasf = (float*)(wsb + 4096);
  bf16*  meas  = (bf16*)(wsb + 32768);
  float* encf  = (float*)(wsb + 294912);
  bf16*  P     = (bf16*)(wsb + 4489216);
  bf16*  Q     = (bf16*)(wsb + 12877824);
  bf16*  WT    = (bf16*)(wsb + 17072128);
  bf16*  Xb    = (bf16*)(wsb + 30253056);
  const bool have_xb = ws_size >= 51224576;

  bf16* ew1t = WT + 0;
  bf16* ew2t = WT + 2621440;
  bf16* ew3t = WT + 3145728;
  bf16* dw1t = WT + 3276800;
  bf16* dw2t = WT + 3280896;
  bf16* dw3t = WT + 3313664;
  bf16* dw4t = WT + 3444736;
  bf16* dw5t = WT + 3969024;
  float* beb1 = biasf + 0;
  float* beb2 = biasf + 1024;
  float* beb3 = biasf + 1536;
  float* bdb1 = biasf + 1792;
  float* bdb2 = biasf + 1920;
  float* bdb3 = biasf + 2176;
  float* bdb4 = biasf + 2688;
  float* bdb5 = biasf + 3712;

  prep_all<<<6445, 256, 0, stream>>>(
      (const float*)d_in[1], (const float*)d_in[3], (const float*)d_in[5],
      (const float*)d_in[8], (const float*)d_in[10], (const float*)d_in[12],
      (const float*)d_in[14], (const float*)d_in[16],
      (const float*)d_in[2], (const float*)d_in[4], (const float*)d_in[6],
      (const float*)d_in[9], (const float*)d_in[11], (const float*)d_in[13],
      (const float*)d_in[15], (const float*)d_in[17],
      (const float*)d_in[7], WT, biasf, gw);

  // ---- GEMM1: h1 = leaky(x @ ew1 + eb1)   [4096x1024, K=2560]
  if (have_xb) {
    cvt_f32_bf16<<<5120, 256, 0, stream>>>((const float*)d_in[0], Xb, 10485760L);
    gemm_async<128, 64, 4, 1, 0, bf16><<<dim3(16, 32), 256, 0, stream>>>(
        Xb, ew1t, beb1, P, 4096, 1024, 2560);
  } else {
    gemm_cvt<<<dim3(8, 32), 256, 0, stream>>>(
        (const float*)d_in[0], (const float*)d_in[1], beb1, P, 4096, 1024, 2560);
  }

  // ---- GEMM2: h2 = leaky(h1 @ ew2 + eb2)  [4096x512, K=1024]
  gemm_async<64, 64, 2, 2, 0, bf16><<<dim3(8, 64), 256, 0, stream>>>(
      P, ew2t, beb2, Q, 4096, 512, 1024);
  // ---- GEMM3: enc = tanh(h2 @ ew3 + eb3)  [4096x256, K=512] -> f32
  gemm_async<64, 64, 2, 2, 1, float><<<dim3(4, 64), 256, 0, stream>>>(
      Q, ew3t, beb3, encf, 4096, 256, 512);

  // ---- quantum circuit -> meas bf16 [4096][32] (24 used, rest zero)
  circuit_kernel<<<4096, 256, 0, stream>>>(encf, gw, meas);

  // ---- decoder
  gemm_async<64, 64, 2, 2, 0, bf16><<<dim3(2, 64), 256, 0, stream>>>(
      meas, dw1t, bdb1, Q, 4096, 128, 32);
  gemm_async<64, 64, 2, 2, 0, bf16><<<dim3(4, 64), 256, 0, stream>>>(
      Q, dw2t, bdb2, P, 4096, 256, 128);
  gemm_async<64, 64, 2, 2, 0, bf16><<<dim3(8, 64), 256, 0, stream>>>(
      P, dw3t, bdb3, Q, 4096, 512, 256);
  gemm_async<128, 64, 4, 1, 0, bf16><<<dim3(16, 32), 256, 0, stream>>>(
      Q, dw4t, bdb4, P, 4096, 1024, 512);
  // ---- d5: out = tanh(d4 @ dw5 + db5)  [4096x2560, K=1024] -> f32
  gemm_async<128, 128, 2, 2, 1, float><<<dim3(20, 32), 256, 0, stream>>>(
      P, dw5t, bdb5, (float*)d_out, 4096, 2560, 1024);
}

// Round 6
// 322.430 us; speedup vs baseline: 4.1608x; 1.1395x over previous
//
#include <hip/hip_runtime.h>
#include <hip/hip_bf16.h>

// f32-storage implementation; circuit = 1 wave/batch-element in registers.
// ws layout (bytes):
//   [256)        gates: 384 f32
//   [4096)       biasf: 6272 f32
//   [32768)      meas  bf16 [4096][32] (cols 24..31 zero)   ends   294,912
//   [294912)     encf  f32  [4096][256]                     ends 4,489,216
//   [4489216)    P     bf16 4096x1024 (h1,d2,d4)            ends 12,877,824
//   [12877824)   Q     bf16 4096x512  (h2,d1,d3)            ends 17,072,128
//   [17072128)   WT    bf16 transposed weights (13.18 MB)   ends 30,253,056
//   [30253056)   Xb    bf16 4096x2560 (x converted)         ends 51,224,576

using bf16 = __hip_bfloat16;
typedef __attribute__((ext_vector_type(8))) short short8;
typedef __attribute__((ext_vector_type(4))) short short4v;
typedef __attribute__((ext_vector_type(4))) float f32x4;

__device__ inline void stf(float* p, size_t i, float v) { p[i] = v; }
__device__ inline void stf(bf16* p, size_t i, float v) { p[i] = __float2bfloat16(v); }

__device__ inline short f2bs(float x) {
  bf16 h = __float2bfloat16(x);
  return *reinterpret_cast<short*>(&h);
}
__device__ inline short8 ld8b(const float* p) {
  const float4 a = ((const float4*)p)[0];
  const float4 b = ((const float4*)p)[1];
  short8 r;
  r[0] = f2bs(a.x); r[1] = f2bs(a.y); r[2] = f2bs(a.z); r[3] = f2bs(a.w);
  r[4] = f2bs(b.x); r[5] = f2bs(b.y); r[6] = f2bs(b.z); r[7] = f2bs(b.w);
  return r;
}
__device__ inline short4v ld4b(const float* p) {
  const float4 a = *(const float4*)p;
  short4v r;
  r[0] = f2bs(a.x); r[1] = f2bs(a.y); r[2] = f2bs(a.z); r[3] = f2bs(a.w);
  return r;
}

__device__ inline void async_load16(const bf16* g, short* l) {
  __builtin_amdgcn_global_load_lds(
      (const __attribute__((address_space(1))) unsigned int*)g,
      (__attribute__((address_space(3))) unsigned int*)l, 16, 0, 0);
}

// ---------------- x f32 -> bf16 bulk convert
__global__ __launch_bounds__(256) void cvt_f32_bf16(const float* __restrict__ in,
                                                    bf16* __restrict__ out, long n) {
  long i = ((long)blockIdx.x * 256 + threadIdx.x) * 8;
  if (i >= n) return;
  short8 v = ld8b(in + i);
  *(short8*)((short*)out + i) = v;
}

// ---------------- prep: transpose weights -> WT bf16 [N][Kp], biases, gates
__global__ __launch_bounds__(256) void prep_all(
    const float* w0, const float* w1, const float* w2, const float* w3,
    const float* w4, const float* w5, const float* w6, const float* w7,
    const float* b0, const float* b1, const float* b2, const float* b3,
    const float* b4, const float* b5, const float* b6, const float* b7,
    const float* dp,
    bf16* __restrict__ wt, float* __restrict__ biasf, float* __restrict__ gw) {
  const int bid = blockIdx.x;
  const int tid = threadIdx.x;
  const int Ks[8]  = {2560, 1024, 512, 24, 128, 256, 512, 1024};
  const int Ns[8]  = {1024, 512, 256, 128, 256, 512, 1024, 2560};
  const int cum[8] = {2560, 3072, 3200, 3204, 3236, 3364, 3876, 6436};
  const long wto[8] = {0, 2621440, 3145728, 3276800, 3280896, 3313664, 3444736, 3969024};
  const float* Wp[8] = {w0, w1, w2, w3, w4, w5, w6, w7};
  const float* Bp[8] = {b0, b1, b2, b3, b4, b5, b6, b7};
  const int boff[8] = {0, 1024, 1536, 1792, 1920, 2176, 2688, 3712};

  if (bid < 6436) {
    int t = 0;
    while (bid >= cum[t]) t++;
    int base = t ? cum[t - 1] : 0;
    int local = bid - base;
    int K = Ks[t], N = Ns[t];
    int tk = (K + 31) >> 5;
    int kt = local % tk, nt = local / tk;
    int Kp = tk << 5;
    __shared__ short tile[32][33];
    int r = tid >> 3, c4 = (tid & 7) << 2;
    int gk = kt * 32 + r, gn = nt * 32 + c4;
    short4v v;
    if (gk < K) v = ld4b(Wp[t] + (size_t)gk * N + gn);
    else { v[0] = 0; v[1] = 0; v[2] = 0; v[3] = 0; }
    tile[r][c4] = v[0]; tile[r][c4 + 1] = v[1]; tile[r][c4 + 2] = v[2]; tile[r][c4 + 3] = v[3];
    __syncthreads();
    int n = tid >> 3, k4 = (tid & 7) << 2;
    short4v o;
    o[0] = tile[k4][n]; o[1] = tile[k4 + 1][n]; o[2] = tile[k4 + 2][n]; o[3] = tile[k4 + 3][n];
    *(short4v*)&wt[wto[t] + (size_t)(nt * 32 + n) * Kp + kt * 32 + k4] = o;
  } else if (bid < 6444) {
    int b = bid - 6436;
    int nb = Ns[b];
    for (int t2 = tid; t2 < nb; t2 += 256)
      biasf[boff[b] + t2] = Bp[b][t2];
  } else {
    int g = tid;
    if (g < 48) {
      float phi = dp[g * 3 + 0], theta = dp[g * 3 + 1], omega = dp[g * 3 + 2];
      float c = cosf(0.5f * theta), s = sinf(0.5f * theta);
      float a = 0.5f * (phi + omega), d = 0.5f * (phi - omega);
      float ca = cosf(a), sa = sinf(a), cd = cosf(d), sd = sinf(d);
      float* o = gw + g * 8;
      o[0] =  ca * c; o[1] = -sa * c;
      o[2] = -cd * s; o[3] = -sd * s;
      o[4] =  cd * s; o[5] = -sd * s;
      o[6] =  ca * c; o[7] =  sa * c;
    }
  }
}

// ---------------- async MFMA GEMM: C = act(A @ Bt^T + bias)
template <int BM, int BN, int WR, int WC, int ACT, typename TC>
__global__ __launch_bounds__(256) void gemm_async(const bf16* __restrict__ A,
                                                  const bf16* __restrict__ Bt,
                                                  const float* __restrict__ bias,
                                                  TC* __restrict__ C,
                                                  int M, int N, int K) {
  constexpr int WMT = BM / WR;
  constexpr int WNT = BN / WC;
  constexpr int FI = WMT / 16;
  constexpr int FJ = WNT / 16;
  __shared__ __align__(16) short As[BM * 32];
  __shared__ __align__(16) short Bs[BN * 32];
  const int tid = threadIdx.x;
  const int lane = tid & 63;
  const int wid = tid >> 6;
  const int wm = wid / WC, wn = wid % WC;
  const int bm = blockIdx.y * BM;
  const int bn = blockIdx.x * BN;

  const int st_row = wid * 16 + (lane >> 2);
  const int st_col = (lane & 3) * 8;

  const int frag_m = lane & 15;
  const int frag_k = (lane >> 4) * 8;

  f32x4 acc[FI][FJ] = {};

  for (int k0 = 0; k0 < K; k0 += 32) {
#pragma unroll
    for (int c = 0; c < BM / 64; ++c) {
      const bf16* g = A + (size_t)(bm + c * 64 + st_row) * K + k0 + st_col;
      async_load16(g, &As[(c * 64 + wid * 16) * 32]);
    }
#pragma unroll
    for (int c = 0; c < BN / 64; ++c) {
      const bf16* g = Bt + (size_t)(bn + c * 64 + st_row) * K + k0 + st_col;
      async_load16(g, &Bs[(c * 64 + wid * 16) * 32]);
    }
    __syncthreads();
    short8 af[FI], bfr[FJ];
#pragma unroll
    for (int i = 0; i < FI; ++i)
      af[i] = *(const short8*)&As[(wm * WMT + i * 16 + frag_m) * 32 + frag_k];
#pragma unroll
    for (int j = 0; j < FJ; ++j)
      bfr[j] = *(const short8*)&Bs[(wn * WNT + j * 16 + frag_m) * 32 + frag_k];
#pragma unroll
    for (int i = 0; i < FI; ++i)
#pragma unroll
      for (int j = 0; j < FJ; ++j)
        acc[i][j] = __builtin_amdgcn_mfma_f32_16x16x32_bf16(af[i], bfr[j], acc[i][j], 0, 0, 0);
    __syncthreads();
  }

  const int col_lane = lane & 15;
  const int row_quad = (lane >> 4) << 2;
#pragma unroll
  for (int i = 0; i < FI; ++i) {
#pragma unroll
    for (int j = 0; j < FJ; ++j) {
      int n = bn + wn * WNT + j * 16 + col_lane;
      float bj = bias[n];
#pragma unroll
      for (int r = 0; r < 4; ++r) {
        int m = bm + wm * WMT + i * 16 + row_quad + r;
        float v = acc[i][j][r] + bj;
        if (ACT == 0) v = (v >= 0.f) ? v : 0.2f * v;
        else v = tanhf(v);
        stf(C, (size_t)m * N + n, v);
      }
    }
  }
}

// ---------------- fallback GEMM1 (f32 A and W) — used only if ws too small
__global__ __launch_bounds__(256) void gemm_cvt(const float* __restrict__ A,
                                                const float* __restrict__ W,
                                                const float* __restrict__ bias,
                                                bf16* __restrict__ C,
                                                int M, int N, int K) {
  __shared__ __align__(16) short As[128 * 40];
  __shared__ __align__(16) short Bs[128 * 40];
  const int tid = threadIdx.x;
  const int lane = tid & 63;
  const int wave = tid >> 6;
  const int wm = wave >> 1, wn = wave & 1;
  const int bm = blockIdx.y * 128;
  const int bn = blockIdx.x * 128;
  const int a_row0 = tid >> 2;
  const int a_kcol = (tid & 3) << 3;
  const int b_ncol = (tid & 31) << 2;
  const int b_krow = (tid >> 5) << 2;
  const int frag_m = lane & 15;
  const int frag_k = (lane >> 4) << 3;

  f32x4 acc[4][4] = {};

  for (int k0 = 0; k0 < K; k0 += 32) {
#pragma unroll
    for (int c = 0; c < 2; ++c) {
      const int row = c * 64 + a_row0;
      short8 v = ld8b(A + (size_t)(bm + row) * K + k0 + a_kcol);
      *(short8*)&As[row * 40 + a_kcol] = v;
    }
    short4v bv[4];
#pragma unroll
    for (int kk = 0; kk < 4; ++kk)
      bv[kk] = ld4b(W + (size_t)(k0 + b_krow + kk) * N + bn + b_ncol);
#pragma unroll
    for (int nn = 0; nn < 4; ++nn) {
      short4v w;
      w[0] = bv[0][nn]; w[1] = bv[1][nn]; w[2] = bv[2][nn]; w[3] = bv[3][nn];
      *(short4v*)&Bs[(b_ncol + nn) * 40 + b_krow] = w;
    }
    __syncthreads();
    short8 af[4], bfr[4];
#pragma unroll
    for (int i = 0; i < 4; ++i)
      af[i] = *(const short8*)&As[(wm * 64 + i * 16 + frag_m) * 40 + frag_k];
#pragma unroll
    for (int j = 0; j < 4; ++j)
      bfr[j] = *(const short8*)&Bs[(wn * 64 + j * 16 + frag_m) * 40 + frag_k];
#pragma unroll
    for (int i = 0; i < 4; ++i)
#pragma unroll
      for (int j = 0; j < 4; ++j)
        acc[i][j] = __builtin_amdgcn_mfma_f32_16x16x32_bf16(af[i], bfr[j], acc[i][j], 0, 0, 0);
    __syncthreads();
  }

  const int col_lane = lane & 15;
  const int row_quad = (lane >> 4) << 2;
#pragma unroll
  for (int i = 0; i < 4; ++i)
#pragma unroll
    for (int j = 0; j < 4; ++j) {
      int n = bn + wn * 64 + j * 16 + col_lane;
      float bj = bias[n];
#pragma unroll
      for (int r = 0; r < 4; ++r) {
        int m = bm + wm * 64 + i * 16 + row_quad + r;
        float v = acc[i][j][r] + bj;
        v = (v >= 0.f) ? v : 0.2f * v;
        stf(C, (size_t)m * N + n, v);
      }
    }
}

// ---------------- circuit: 1 wave per batch element, statevector in VGPRs.
// Lane L slot j holds amplitude index i = L*4+j (slot = flat bits 0-1).
// Qubit q has flat-bit stride s = 1<<(7-q): s>=4 -> lane exchange via
// shfl_xor(s>>2); s<4 -> in-register slot ops. No __syncthreads in the body.
__global__ __launch_bounds__(256) void circuit_wave(const float* __restrict__ enc,
                                                    const float* __restrict__ gw,
                                                    bf16* __restrict__ meas) {
  __shared__ float gsh[384];
  const int tid = threadIdx.x;
  for (int t = tid; t < 384; t += 256) gsh[t] = gw[t];
  __syncthreads();
  const int lane = tid & 63;
  const int b = blockIdx.x * 4 + (tid >> 6);

  float4 e = *(const float4*)(enc + (size_t)b * 256 + lane * 4);
  float re[4] = {e.x, e.y, e.z, e.w};
  float im[4] = {0.f, 0.f, 0.f, 0.f};
  float ss = e.x * e.x + e.y * e.y + e.z * e.z + e.w * e.w;
#pragma unroll
  for (int o = 32; o; o >>= 1) ss += __shfl_xor(ss, o, 64);
  float inv = 1.0f / fmaxf(sqrtf(ss), 1e-12f);
#pragma unroll
  for (int j = 0; j < 4; ++j) re[j] *= inv;

  for (int l = 0; l < 6; ++l) {
    // --- 8 Rot gates
    for (int q = 0; q < 8; ++q) {
      const float* g = &gsh[(l * 8 + q) * 8];
      const int s = 1 << (7 - q);
      if (s >= 4) {
        const int lm = s >> 2;
        const bool hi = (lane & lm) != 0;
        const float g0r = hi ? g[4] : g[0], g0i = hi ? g[5] : g[1];
        const float g1r = hi ? g[6] : g[2], g1i = hi ? g[7] : g[3];
#pragma unroll
        for (int j = 0; j < 4; ++j) {
          float orr = __shfl_xor(re[j], lm, 64);
          float oii = __shfl_xor(im[j], lm, 64);
          float p0r = hi ? orr : re[j], p0i = hi ? oii : im[j];
          float p1r = hi ? re[j] : orr, p1i = hi ? im[j] : oii;
          re[j] = g0r * p0r - g0i * p0i + g1r * p1r - g1i * p1i;
          im[j] = g0r * p0i + g0i * p0r + g1r * p1i + g1i * p1r;
        }
      } else {
#pragma unroll
        for (int j0 = 0; j0 < 4; ++j0) {
          if ((j0 & s) == 0) {
            int j1 = j0 | s;
            float p0r = re[j0], p0i = im[j0], p1r = re[j1], p1i = im[j1];
            re[j0] = g[0] * p0r - g[1] * p0i + g[2] * p1r - g[3] * p1i;
            im[j0] = g[0] * p0i + g[1] * p0r + g[2] * p1i + g[3] * p1r;
            re[j1] = g[4] * p0r - g[5] * p0i + g[6] * p1r - g[7] * p1i;
            im[j1] = g[4] * p0i + g[5] * p0r + g[6] * p1i + g[7] * p1r;
          }
        }
      }
    }
    // --- CNOT ring, range r
    const int r = l % 7 + 1;
    for (int q = 0; q < 8; ++q) {
      const int sc = 1 << (7 - q);
      const int st = 1 << (7 - ((q + r) & 7));
      if (st >= 4) {
        const int lm = st >> 2;
        if (sc >= 4) {
          const bool ctl = (lane & (sc >> 2)) != 0;
#pragma unroll
          for (int j = 0; j < 4; ++j) {
            float orr = __shfl_xor(re[j], lm, 64);
            float oii = __shfl_xor(im[j], lm, 64);
            re[j] = ctl ? orr : re[j];
            im[j] = ctl ? oii : im[j];
          }
        } else {
#pragma unroll
          for (int j = 0; j < 4; ++j) {
            if (j & sc) {  // wave-uniform condition after unroll
              re[j] = __shfl_xor(re[j], lm, 64);
              im[j] = __shfl_xor(im[j], lm, 64);
            }
          }
        }
      } else {
        if (sc >= 4) {
          const bool ctl = (lane & (sc >> 2)) != 0;
#pragma unroll
          for (int j0 = 0; j0 < 4; ++j0) {
            if ((j0 & st) == 0) {
              int j1 = j0 | st;
              float t0r = re[j0], t0i = im[j0];
              float t1r = re[j1], t1i = im[j1];
              re[j0] = ctl ? t1r : t0r; im[j0] = ctl ? t1i : t0i;
              re[j1] = ctl ? t0r : t1r; im[j1] = ctl ? t0i : t1i;
            }
          }
        } else {
#pragma unroll
          for (int j0 = 0; j0 < 4; ++j0) {
            if ((j0 & sc) && (j0 & st) == 0) {
              int j1 = j0 | st;
              float tr = re[j0], ti = im[j0];
              re[j0] = re[j1]; im[j0] = im[j1];
              re[j1] = tr; im[j1] = ti;
            }
          }
        }
      }
    }
  }

  // --- measurements: Z (0..7), X (8..15), Y (16..23)
  for (int q = 0; q < 8; ++q) {
    const int s = 1 << (7 - q);
    float z = 0.f, x = 0.f, y = 0.f;
#pragma unroll
    for (int j = 0; j < 4; ++j) {
      float fr, fi;
      if (s >= 4) {
        fr = __shfl_xor(re[j], s >> 2, 64);
        fi = __shfl_xor(im[j], s >> 2, 64);
      } else {
        fr = re[j ^ s]; fi = im[j ^ s];
      }
      float prob = re[j] * re[j] + im[j] * im[j];
      int i = lane * 4 + j;
      float sg = (i & s) ? -1.f : 1.f;
      z += sg * prob;
      x += re[j] * fr + im[j] * fi;
      y += sg * (re[j] * fi - im[j] * fr);
    }
#pragma unroll
    for (int o = 32; o; o >>= 1) {
      z += __shfl_xor(z, o, 64);
      x += __shfl_xor(x, o, 64);
      y += __shfl_xor(y, o, 64);
    }
    if (lane == 0) {
      meas[(size_t)b * 32 + q]      = __float2bfloat16(z);
      meas[(size_t)b * 32 + 8 + q]  = __float2bfloat16(x);
      meas[(size_t)b * 32 + 16 + q] = __float2bfloat16(y);
    }
  }
  if (lane >= 24 && lane < 32)
    meas[(size_t)b * 32 + lane] = __float2bfloat16(0.f);
}

extern "C" void kernel_launch(void* const* d_in, const int* in_sizes, int n_in,
                              void* d_out, int out_size, void* d_ws, size_t ws_size,
                              hipStream_t stream) {
  (void)in_sizes; (void)n_in; (void)out_size;
  char* wsb = (char*)d_ws;
  float* gw    = (float*)(wsb + 256);
  float* biasf = (float*)(wsb + 4096);
  bf16*  meas  = (bf16*)(wsb + 32768);
  float* encf  = (float*)(wsb + 294912);
  bf16*  P     = (bf16*)(wsb + 4489216);
  bf16*  Q     = (bf16*)(wsb + 12877824);
  bf16*  WT    = (bf16*)(wsb + 17072128);
  bf16*  Xb    = (bf16*)(wsb + 30253056);
  const bool have_xb = ws_size >= 51224576;

  bf16* ew1t = WT + 0;
  bf16* ew2t = WT + 2621440;
  bf16* ew3t = WT + 3145728;
  bf16* dw1t = WT + 3276800;
  bf16* dw2t = WT + 3280896;
  bf16* dw3t = WT + 3313664;
  bf16* dw4t = WT + 3444736;
  bf16* dw5t = WT + 3969024;
  float* beb1 = biasf + 0;
  float* beb2 = biasf + 1024;
  float* beb3 = biasf + 1536;
  float* bdb1 = biasf + 1792;
  float* bdb2 = biasf + 1920;
  float* bdb3 = biasf + 2176;
  float* bdb4 = biasf + 2688;
  float* bdb5 = biasf + 3712;

  prep_all<<<6445, 256, 0, stream>>>(
      (const float*)d_in[1], (const float*)d_in[3], (const float*)d_in[5],
      (const float*)d_in[8], (const float*)d_in[10], (const float*)d_in[12],
      (const float*)d_in[14], (const float*)d_in[16],
      (const float*)d_in[2], (const float*)d_in[4], (const float*)d_in[6],
      (const float*)d_in[9], (const float*)d_in[11], (const float*)d_in[13],
      (const float*)d_in[15], (const float*)d_in[17],
      (const float*)d_in[7], WT, biasf, gw);

  // ---- GEMM1: h1 = leaky(x @ ew1 + eb1)   [4096x1024, K=2560]
  if (have_xb) {
    cvt_f32_bf16<<<5120, 256, 0, stream>>>((const float*)d_in[0], Xb, 10485760L);
    gemm_async<128, 64, 4, 1, 0, bf16><<<dim3(16, 32), 256, 0, stream>>>(
        Xb, ew1t, beb1, P, 4096, 1024, 2560);
  } else {
    gemm_cvt<<<dim3(8, 32), 256, 0, stream>>>(
        (const float*)d_in[0], (const float*)d_in[1], beb1, P, 4096, 1024, 2560);
  }

  // ---- GEMM2: h2 = leaky(h1 @ ew2 + eb2)  [4096x512, K=1024]
  gemm_async<64, 64, 2, 2, 0, bf16><<<dim3(8, 64), 256, 0, stream>>>(
      P, ew2t, beb2, Q, 4096, 512, 1024);
  // ---- GEMM3: enc = tanh(h2 @ ew3 + eb3)  [4096x256, K=512] -> f32
  gemm_async<64, 64, 2, 2, 1, float><<<dim3(4, 64), 256, 0, stream>>>(
      Q, ew3t, beb3, encf, 4096, 256, 512);

  // ---- quantum circuit -> meas bf16 [4096][32] (24 used, rest zero)
  circuit_wave<<<1024, 256, 0, stream>>>(encf, gw, meas);

  // ---- decoder
  gemm_async<64, 64, 2, 2, 0, bf16><<<dim3(2, 64), 256, 0, stream>>>(
      meas, dw1t, bdb1, Q, 4096, 128, 32);
  gemm_async<64, 64, 2, 2, 0, bf16><<<dim3(4, 64), 256, 0, stream>>>(
      Q, dw2t, bdb2, P, 4096, 256, 128);
  gemm_async<64, 64, 2, 2, 0, bf16><<<dim3(8, 64), 256, 0, stream>>>(
      P, dw3t, bdb3, Q, 4096, 512, 256);
  gemm_async<128, 64, 4, 1, 0, bf16><<<dim3(16, 32), 256, 0, stream>>>(
      Q, dw4t, bdb4, P, 4096, 1024, 512);
  // ---- d5: out = tanh(d4 @ dw5 + db5)  [4096x2560, K=1024] -> f32
  gemm_async<128, 128, 2, 2, 1, float><<<dim3(20, 32), 256, 0, stream>>>(
      P, dw5t, bdb5, (float*)d_out, 4096, 2560, 1024);
}

// Round 7
// 309.822 us; speedup vs baseline: 4.3301x; 1.0407x over previous
//
#include <hip/hip_runtime.h>
#include <hip/hip_bf16.h>

// f32-storage implementation. BK=64 async GEMM with XOR-swizzled LDS.
// ws layout (bytes):
//   [256)        gates: 384 f32
//   [4096)       biasf: 6272 f32
//   [32768)      meas  bf16 [4096][32] (cols 24..31 zero)   ends   294,912
//   [294912)     encf  f32  [4096][256]                     ends 4,489,216
//   [4489216)    P     bf16 4096x1024 (h1,d2,d4)            ends 12,877,824
//   [12877824)   Q     bf16 4096x512  (h2,d1,d3)            ends 17,072,128
//   [17072128)   WT    bf16 transposed weights (13.18 MB)   ends 30,253,056
//   [30253056)   Xb    bf16 4096x2560 (x converted)         ends 51,224,576

using bf16 = __hip_bfloat16;
typedef __attribute__((ext_vector_type(8))) short short8;
typedef __attribute__((ext_vector_type(4))) short short4v;
typedef __attribute__((ext_vector_type(4))) float f32x4;

__device__ inline void stf(float* p, size_t i, float v) { p[i] = v; }
__device__ inline void stf(bf16* p, size_t i, float v) { p[i] = __float2bfloat16(v); }

__device__ inline short f2bs(float x) {
  bf16 h = __float2bfloat16(x);
  return *reinterpret_cast<short*>(&h);
}
__device__ inline short8 ld8b(const float* p) {
  const float4 a = ((const float4*)p)[0];
  const float4 b = ((const float4*)p)[1];
  short8 r;
  r[0] = f2bs(a.x); r[1] = f2bs(a.y); r[2] = f2bs(a.z); r[3] = f2bs(a.w);
  r[4] = f2bs(b.x); r[5] = f2bs(b.y); r[6] = f2bs(b.z); r[7] = f2bs(b.w);
  return r;
}
__device__ inline short4v ld4b(const float* p) {
  const float4 a = *(const float4*)p;
  short4v r;
  r[0] = f2bs(a.x); r[1] = f2bs(a.y); r[2] = f2bs(a.z); r[3] = f2bs(a.w);
  return r;
}

__device__ inline void async_load16(const bf16* g, short* l) {
  __builtin_amdgcn_global_load_lds(
      (const __attribute__((address_space(1))) unsigned int*)g,
      (__attribute__((address_space(3))) unsigned int*)l, 16, 0, 0);
}

// ---------------- prep: weights -> WT bf16 [N][Kp]; biases; gates; x -> bf16
__global__ __launch_bounds__(256) void prep_all(
    const float* w0, const float* w1, const float* w2, const float* w3,
    const float* w4, const float* w5, const float* w6, const float* w7,
    const float* b0, const float* b1, const float* b2, const float* b3,
    const float* b4, const float* b5, const float* b6, const float* b7,
    const float* dp, const float* xf,
    bf16* __restrict__ wt, float* __restrict__ biasf, float* __restrict__ gw,
    bf16* __restrict__ xb, int do_x) {
  const int bid = blockIdx.x;
  const int tid = threadIdx.x;
  const int Ks[8]  = {2560, 1024, 512, 24, 128, 256, 512, 1024};
  const int Ns[8]  = {1024, 512, 256, 128, 256, 512, 1024, 2560};
  const int cum[8] = {2560, 3072, 3200, 3204, 3236, 3364, 3876, 6436};
  const long wto[8] = {0, 2621440, 3145728, 3276800, 3280896, 3313664, 3444736, 3969024};
  const float* Wp[8] = {w0, w1, w2, w3, w4, w5, w6, w7};
  const float* Bp[8] = {b0, b1, b2, b3, b4, b5, b6, b7};
  const int boff[8] = {0, 1024, 1536, 1792, 1920, 2176, 2688, 3712};

  if (bid < 6436) {
    int t = 0;
    while (bid >= cum[t]) t++;
    int base = t ? cum[t - 1] : 0;
    int local = bid - base;
    int K = Ks[t], N = Ns[t];
    int tk = (K + 31) >> 5;
    int kt = local % tk, nt = local / tk;
    int Kp = tk << 5;
    __shared__ short tile[32][33];
    int r = tid >> 3, c4 = (tid & 7) << 2;
    int gk = kt * 32 + r, gn = nt * 32 + c4;
    short4v v;
    if (gk < K) v = ld4b(Wp[t] + (size_t)gk * N + gn);
    else { v[0] = 0; v[1] = 0; v[2] = 0; v[3] = 0; }
    tile[r][c4] = v[0]; tile[r][c4 + 1] = v[1]; tile[r][c4 + 2] = v[2]; tile[r][c4 + 3] = v[3];
    __syncthreads();
    int n = tid >> 3, k4 = (tid & 7) << 2;
    short4v o;
    o[0] = tile[k4][n]; o[1] = tile[k4 + 1][n]; o[2] = tile[k4 + 2][n]; o[3] = tile[k4 + 3][n];
    *(short4v*)&wt[wto[t] + (size_t)(nt * 32 + n) * Kp + kt * 32 + k4] = o;
  } else if (bid < 6444) {
    int b = bid - 6436;
    int nb = Ns[b];
    for (int t2 = tid; t2 < nb; t2 += 256)
      biasf[boff[b] + t2] = Bp[b][t2];
  } else if (bid == 6444) {
    int g = tid;
    if (g < 48) {
      float phi = dp[g * 3 + 0], theta = dp[g * 3 + 1], omega = dp[g * 3 + 2];
      float c = cosf(0.5f * theta), s = sinf(0.5f * theta);
      float a = 0.5f * (phi + omega), d = 0.5f * (phi - omega);
      float ca = cosf(a), sa = sinf(a), cd = cosf(d), sd = sinf(d);
      float* o = gw + g * 8;
      o[0] =  ca * c; o[1] = -sa * c;
      o[2] = -cd * s; o[3] = -sd * s;
      o[4] =  cd * s; o[5] = -sd * s;
      o[6] =  ca * c; o[7] =  sa * c;
    }
  } else if (do_x) {
    long i = ((long)(bid - 6445) * 256 + tid) * 8;
    if (i < 10485760L) {
      short8 v = ld8b(xf + i);
      *(short8*)((short*)xb + i) = v;
    }
  }
}

// ---------------- async MFMA GEMM: C = act(A @ Bt^T + bias)
// A: [M][K] bf16, Bt: [N][K] bf16. global_load_lds staging, XOR-swizzled
// chunk layout in LDS (stage global chunk c^(r&MASK) into slot c) so the
// frag ds_read_b128s land on distinct banks (2-way max, free).
template <int BM, int BN, int BK, int WR, int WC, int ACT, typename TC>
__global__ __launch_bounds__(256) void gemm_async(const bf16* __restrict__ A,
                                                  const bf16* __restrict__ Bt,
                                                  const float* __restrict__ bias,
                                                  TC* __restrict__ C,
                                                  int M, int N, int K) {
  constexpr int CPR = BK / 8;     // 16B chunks per LDS row
  constexpr int MASK = CPR - 1;
  constexpr int RPW = 64 / CPR;   // rows staged per wave per pass
  constexpr int RPP = 4 * RPW;    // rows per pass (4 waves)
  constexpr int WMT = BM / WR;
  constexpr int WNT = BN / WC;
  constexpr int FI = WMT / 16;
  constexpr int FJ = WNT / 16;
  constexpr int KK = BK / 32;
  __shared__ __align__(16) short As[BM * BK];
  __shared__ __align__(16) short Bs[BN * BK];
  const int tid = threadIdx.x;
  const int lane = tid & 63;
  const int wid = tid >> 6;
  const int wm = wid / WC, wn = wid % WC;
  const int bm = blockIdx.y * BM;
  const int bn = blockIdx.x * BN;

  const int st_r = lane / CPR;                  // row within RPW group
  const int st_cs = (lane & MASK) ^ (st_r & MASK);  // swizzled global chunk

  const int frag_m = lane & 15;
  const int q = lane >> 4;                      // quad id 0..3

  f32x4 acc[FI][FJ] = {};

  for (int k0 = 0; k0 < K; k0 += BK) {
#pragma unroll
    for (int p = 0; p < BM / RPP; ++p) {
      const bf16* g = A + (size_t)(bm + p * RPP + wid * RPW + st_r) * K + k0 + st_cs * 8;
      async_load16(g, &As[(p * RPP + wid * RPW) * BK]);
    }
#pragma unroll
    for (int p = 0; p < BN / RPP; ++p) {
      const bf16* g = Bt + (size_t)(bn + p * RPP + wid * RPW + st_r) * K + k0 + st_cs * 8;
      async_load16(g, &Bs[(p * RPP + wid * RPW) * BK]);
    }
    __syncthreads();
    short8 af[FI][KK], bfr[FJ][KK];
#pragma unroll
    for (int i = 0; i < FI; ++i) {
      const int m = wm * WMT + i * 16 + frag_m;
#pragma unroll
      for (int kk = 0; kk < KK; ++kk) {
        const int slot = (kk * 4 + q) ^ (m & MASK);
        af[i][kk] = *(const short8*)&As[m * BK + slot * 8];
      }
    }
#pragma unroll
    for (int j = 0; j < FJ; ++j) {
      const int n = wn * WNT + j * 16 + frag_m;
#pragma unroll
      for (int kk = 0; kk < KK; ++kk) {
        const int slot = (kk * 4 + q) ^ (n & MASK);
        bfr[j][kk] = *(const short8*)&Bs[n * BK + slot * 8];
      }
    }
#pragma unroll
    for (int kk = 0; kk < KK; ++kk)
#pragma unroll
      for (int i = 0; i < FI; ++i)
#pragma unroll
        for (int j = 0; j < FJ; ++j)
          acc[i][j] = __builtin_amdgcn_mfma_f32_16x16x32_bf16(af[i][kk], bfr[j][kk], acc[i][j], 0, 0, 0);
    __syncthreads();
  }

  const int col_lane = lane & 15;
  const int row_quad = q << 2;
#pragma unroll
  for (int i = 0; i < FI; ++i) {
#pragma unroll
    for (int j = 0; j < FJ; ++j) {
      int n = bn + wn * WNT + j * 16 + col_lane;
      float bj = bias[n];
#pragma unroll
      for (int r = 0; r < 4; ++r) {
        int m = bm + wm * WMT + i * 16 + row_quad + r;
        float v = acc[i][j][r] + bj;
        if (ACT == 0) v = (v >= 0.f) ? v : 0.2f * v;
        else v = tanhf(v);
        stf(C, (size_t)m * N + n, v);
      }
    }
  }
}

// ---------------- fallback GEMM1 (f32 A and W) — used only if ws too small
__global__ __launch_bounds__(256) void gemm_cvt(const float* __restrict__ A,
                                                const float* __restrict__ W,
                                                const float* __restrict__ bias,
                                                bf16* __restrict__ C,
                                                int M, int N, int K) {
  __shared__ __align__(16) short As[128 * 40];
  __shared__ __align__(16) short Bs[128 * 40];
  const int tid = threadIdx.x;
  const int lane = tid & 63;
  const int wave = tid >> 6;
  const int wm = wave >> 1, wn = wave & 1;
  const int bm = blockIdx.y * 128;
  const int bn = blockIdx.x * 128;
  const int a_row0 = tid >> 2;
  const int a_kcol = (tid & 3) << 3;
  const int b_ncol = (tid & 31) << 2;
  const int b_krow = (tid >> 5) << 2;
  const int frag_m = lane & 15;
  const int frag_k = (lane >> 4) << 3;

  f32x4 acc[4][4] = {};

  for (int k0 = 0; k0 < K; k0 += 32) {
#pragma unroll
    for (int c = 0; c < 2; ++c) {
      const int row = c * 64 + a_row0;
      short8 v = ld8b(A + (size_t)(bm + row) * K + k0 + a_kcol);
      *(short8*)&As[row * 40 + a_kcol] = v;
    }
    short4v bv[4];
#pragma unroll
    for (int kk = 0; kk < 4; ++kk)
      bv[kk] = ld4b(W + (size_t)(k0 + b_krow + kk) * N + bn + b_ncol);
#pragma unroll
    for (int nn = 0; nn < 4; ++nn) {
      short4v w;
      w[0] = bv[0][nn]; w[1] = bv[1][nn]; w[2] = bv[2][nn]; w[3] = bv[3][nn];
      *(short4v*)&Bs[(b_ncol + nn) * 40 + b_krow] = w;
    }
    __syncthreads();
    short8 af[4], bfr[4];
#pragma unroll
    for (int i = 0; i < 4; ++i)
      af[i] = *(const short8*)&As[(wm * 64 + i * 16 + frag_m) * 40 + frag_k];
#pragma unroll
    for (int j = 0; j < 4; ++j)
      bfr[j] = *(const short8*)&Bs[(wn * 64 + j * 16 + frag_m) * 40 + frag_k];
#pragma unroll
    for (int i = 0; i < 4; ++i)
#pragma unroll
      for (int j = 0; j < 4; ++j)
        acc[i][j] = __builtin_amdgcn_mfma_f32_16x16x32_bf16(af[i], bfr[j], acc[i][j], 0, 0, 0);
    __syncthreads();
  }

  const int col_lane = lane & 15;
  const int row_quad = (lane >> 4) << 2;
#pragma unroll
  for (int i = 0; i < 4; ++i)
#pragma unroll
    for (int j = 0; j < 4; ++j) {
      int n = bn + wn * 64 + j * 16 + col_lane;
      float bj = bias[n];
#pragma unroll
      for (int r = 0; r < 4; ++r) {
        int m = bm + wm * 64 + i * 16 + row_quad + r;
        float v = acc[i][j][r] + bj;
        v = (v >= 0.f) ? v : 0.2f * v;
        stf(C, (size_t)m * N + n, v);
      }
    }
}

// ---------------- circuit: 1 wave per batch element, statevector in VGPRs.
__global__ __launch_bounds__(256) void circuit_wave(const float* __restrict__ enc,
                                                    const float* __restrict__ gw,
                                                    bf16* __restrict__ meas) {
  __shared__ float gsh[384];
  const int tid = threadIdx.x;
  for (int t = tid; t < 384; t += 256) gsh[t] = gw[t];
  __syncthreads();
  const int lane = tid & 63;
  const int b = blockIdx.x * 4 + (tid >> 6);

  float4 e = *(const float4*)(enc + (size_t)b * 256 + lane * 4);
  float re[4] = {e.x, e.y, e.z, e.w};
  float im[4] = {0.f, 0.f, 0.f, 0.f};
  float ss = e.x * e.x + e.y * e.y + e.z * e.z + e.w * e.w;
#pragma unroll
  for (int o = 32; o; o >>= 1) ss += __shfl_xor(ss, o, 64);
  float inv = 1.0f / fmaxf(sqrtf(ss), 1e-12f);
#pragma unroll
  for (int j = 0; j < 4; ++j) re[j] *= inv;

  for (int l = 0; l < 6; ++l) {
    for (int qq = 0; qq < 8; ++qq) {
      const float* g = &gsh[(l * 8 + qq) * 8];
      const int s = 1 << (7 - qq);
      if (s >= 4) {
        const int lm = s >> 2;
        const bool hi = (lane & lm) != 0;
        const float g0r = hi ? g[4] : g[0], g0i = hi ? g[5] : g[1];
        const float g1r = hi ? g[6] : g[2], g1i = hi ? g[7] : g[3];
#pragma unroll
        for (int j = 0; j < 4; ++j) {
          float orr = __shfl_xor(re[j], lm, 64);
          float oii = __shfl_xor(im[j], lm, 64);
          float p0r = hi ? orr : re[j], p0i = hi ? oii : im[j];
          float p1r = hi ? re[j] : orr, p1i = hi ? im[j] : oii;
          re[j] = g0r * p0r - g0i * p0i + g1r * p1r - g1i * p1i;
          im[j] = g0r * p0i + g0i * p0r + g1r * p1i + g1i * p1r;
        }
      } else {
#pragma unroll
        for (int j0 = 0; j0 < 4; ++j0) {
          if ((j0 & s) == 0) {
            int j1 = j0 | s;
            float p0r = re[j0], p0i = im[j0], p1r = re[j1], p1i = im[j1];
            re[j0] = g[0] * p0r - g[1] * p0i + g[2] * p1r - g[3] * p1i;
            im[j0] = g[0] * p0i + g[1] * p0r + g[2] * p1i + g[3] * p1r;
            re[j1] = g[4] * p0r - g[5] * p0i + g[6] * p1r - g[7] * p1i;
            im[j1] = g[4] * p0i + g[5] * p0r + g[6] * p1i + g[7] * p1r;
          }
        }
      }
    }
    const int r = l % 7 + 1;
    for (int qq = 0; qq < 8; ++qq) {
      const int sc = 1 << (7 - qq);
      const int st = 1 << (7 - ((qq + r) & 7));
      if (st >= 4) {
        const int lm = st >> 2;
        if (sc >= 4) {
          const bool ctl = (lane & (sc >> 2)) != 0;
#pragma unroll
          for (int j = 0; j < 4; ++j) {
            float orr = __shfl_xor(re[j], lm, 64);
            float oii = __shfl_xor(im[j], lm, 64);
            re[j] = ctl ? orr : re[j];
            im[j] = ctl ? oii : im[j];
          }
        } else {
#pragma unroll
          for (int j = 0; j < 4; ++j) {
            if (j & sc) {
              re[j] = __shfl_xor(re[j], lm, 64);
              im[j] = __shfl_xor(im[j], lm, 64);
            }
          }
        }
      } else {
        if (sc >= 4) {
          const bool ctl = (lane & (sc >> 2)) != 0;
#pragma unroll
          for (int j0 = 0; j0 < 4; ++j0) {
            if ((j0 & st) == 0) {
              int j1 = j0 | st;
              float t0r = re[j0], t0i = im[j0];
              float t1r = re[j1], t1i = im[j1];
              re[j0] = ctl ? t1r : t0r; im[j0] = ctl ? t1i : t0i;
              re[j1] = ctl ? t0r : t1r; im[j1] = ctl ? t0i : t1i;
            }
          }
        } else {
#pragma unroll
          for (int j0 = 0; j0 < 4; ++j0) {
            if ((j0 & sc) && (j0 & st) == 0) {
              int j1 = j0 | st;
              float tr = re[j0], ti = im[j0];
              re[j0] = re[j1]; im[j0] = im[j1];
              re[j1] = tr; im[j1] = ti;
            }
          }
        }
      }
    }
  }

  for (int qq = 0; qq < 8; ++qq) {
    const int s = 1 << (7 - qq);
    float z = 0.f, x = 0.f, y = 0.f;
#pragma unroll
    for (int j = 0; j < 4; ++j) {
      float fr, fi;
      if (s >= 4) {
        fr = __shfl_xor(re[j], s >> 2, 64);
        fi = __shfl_xor(im[j], s >> 2, 64);
      } else {
        fr = re[j ^ s]; fi = im[j ^ s];
      }
      float prob = re[j] * re[j] + im[j] * im[j];
      int i = lane * 4 + j;
      float sg = (i & s) ? -1.f : 1.f;
      z += sg * prob;
      x += re[j] * fr + im[j] * fi;
      y += sg * (re[j] * fi - im[j] * fr);
    }
#pragma unroll
    for (int o = 32; o; o >>= 1) {
      z += __shfl_xor(z, o, 64);
      x += __shfl_xor(x, o, 64);
      y += __shfl_xor(y, o, 64);
    }
    if (lane == 0) {
      meas[(size_t)b * 32 + qq]      = __float2bfloat16(z);
      meas[(size_t)b * 32 + 8 + qq]  = __float2bfloat16(x);
      meas[(size_t)b * 32 + 16 + qq] = __float2bfloat16(y);
    }
  }
  if (lane >= 24 && lane < 32)
    meas[(size_t)b * 32 + lane] = __float2bfloat16(0.f);
}

extern "C" void kernel_launch(void* const* d_in, const int* in_sizes, int n_in,
                              void* d_out, int out_size, void* d_ws, size_t ws_size,
                              hipStream_t stream) {
  (void)in_sizes; (void)n_in; (void)out_size;
  char* wsb = (char*)d_ws;
  float* gw    = (float*)(wsb + 256);
  float* biasf = (float*)(wsb + 4096);
  bf16*  meas  = (bf16*)(wsb + 32768);
  float* encf  = (float*)(wsb + 294912);
  bf16*  P     = (bf16*)(wsb + 4489216);
  bf16*  Q     = (bf16*)(wsb + 12877824);
  bf16*  WT    = (bf16*)(wsb + 17072128);
  bf16*  Xb    = (bf16*)(wsb + 30253056);
  const bool have_xb = ws_size >= 51224576;

  bf16* ew1t = WT + 0;
  bf16* ew2t = WT + 2621440;
  bf16* ew3t = WT + 3145728;
  bf16* dw1t = WT + 3276800;
  bf16* dw2t = WT + 3280896;
  bf16* dw3t = WT + 3313664;
  bf16* dw4t = WT + 3444736;
  bf16* dw5t = WT + 3969024;
  float* beb1 = biasf + 0;
  float* beb2 = biasf + 1024;
  float* beb3 = biasf + 1536;
  float* bdb1 = biasf + 1792;
  float* bdb2 = biasf + 1920;
  float* bdb3 = biasf + 2176;
  float* bdb4 = biasf + 2688;
  float* bdb5 = biasf + 3712;

  prep_all<<<11565, 256, 0, stream>>>(
      (const float*)d_in[1], (const float*)d_in[3], (const float*)d_in[5],
      (const float*)d_in[8], (const float*)d_in[10], (const float*)d_in[12],
      (const float*)d_in[14], (const float*)d_in[16],
      (const float*)d_in[2], (const float*)d_in[4], (const float*)d_in[6],
      (const float*)d_in[9], (const float*)d_in[11], (const float*)d_in[13],
      (const float*)d_in[15], (const float*)d_in[17],
      (const float*)d_in[7], (const float*)d_in[0],
      WT, biasf, gw, Xb, have_xb ? 1 : 0);

  // ---- GEMM1: h1 = leaky(x @ ew1 + eb1)   [4096x1024, K=2560]
  if (have_xb) {
    gemm_async<128, 64, 64, 4, 1, 0, bf16><<<dim3(16, 32), 256, 0, stream>>>(
        Xb, ew1t, beb1, P, 4096, 1024, 2560);
  } else {
    gemm_cvt<<<dim3(8, 32), 256, 0, stream>>>(
        (const float*)d_in[0], (const float*)d_in[1], beb1, P, 4096, 1024, 2560);
  }

  // ---- GEMM2: h2 = leaky(h1 @ ew2 + eb2)  [4096x512, K=1024]
  gemm_async<64, 64, 64, 2, 2, 0, bf16><<<dim3(8, 64), 256, 0, stream>>>(
      P, ew2t, beb2, Q, 4096, 512, 1024);
  // ---- GEMM3: enc = tanh(h2 @ ew3 + eb3)  [4096x256, K=512] -> f32
  gemm_async<64, 64, 64, 2, 2, 1, float><<<dim3(4, 64), 256, 0, stream>>>(
      Q, ew3t, beb3, encf, 4096, 256, 512);

  // ---- quantum circuit -> meas bf16 [4096][32] (24 used, rest zero)
  circuit_wave<<<1024, 256, 0, stream>>>(encf, gw, meas);

  // ---- decoder
  gemm_async<64, 64, 32, 2, 2, 0, bf16><<<dim3(2, 64), 256, 0, stream>>>(
      meas, dw1t, bdb1, Q, 4096, 128, 32);
  gemm_async<64, 64, 64, 2, 2, 0, bf16><<<dim3(4, 64), 256, 0, stream>>>(
      Q, dw2t, bdb2, P, 4096, 256, 128);
  gemm_async<64, 64, 64, 2, 2, 0, bf16><<<dim3(8, 64), 256, 0, stream>>>(
      P, dw3t, bdb3, Q, 4096, 512, 256);
  gemm_async<128, 64, 64, 4, 1, 0, bf16><<<dim3(16, 32), 256, 0, stream>>>(
      Q, dw4t, bdb4, P, 4096, 1024, 512);
  // ---- d5: out = tanh(d4 @ dw5 + db5)  [4096x2560, K=1024] -> f32
  gemm_async<128, 128, 64, 2, 2, 1, float><<<dim3(20, 32), 256, 0, stream>>>(
      P, dw5t, bdb5, (float*)d_out, 4096, 2560, 1024);
}

// Round 8
// 308.107 us; speedup vs baseline: 4.3542x; 1.0056x over previous
//
#include <hip/hip_runtime.h>
#include <hip/hip_bf16.h>

// f32-storage implementation. BK=64 async GEMM, XOR-swizzled LDS, fast-tanh
// epilogues, d1 fused into the circuit kernel.
// ws layout (bytes):
//   [256)        gates: 384 f32
//   [4096)       biasf: 6272 f32
//   [294912)     encf  f32  [4096][256]                     ends 4,489,216
//   [4489216)    P     bf16 4096x1024 (h1,d2,d4)            ends 12,877,824
//   [12877824)   Q     bf16 4096x512  (h2,d1,d3)            ends 17,072,128
//   [17072128)   WT    bf16 transposed weights (13.18 MB)   ends 30,253,056
//   [30253056)   Xb    bf16 4096x2560 (x converted)         ends 51,224,576

using bf16 = __hip_bfloat16;
typedef __attribute__((ext_vector_type(8))) short short8;
typedef __attribute__((ext_vector_type(4))) short short4v;
typedef __attribute__((ext_vector_type(4))) float f32x4;

__device__ inline void stf(float* p, size_t i, float v) { p[i] = v; }
__device__ inline void stf(bf16* p, size_t i, float v) { p[i] = __float2bfloat16(v); }

// fast tanh: ~5 VALU ops, clamped so exp stays finite (no inf/inf NaN).
// |err| ~1e-6, far below the bf16-level output threshold.
__device__ inline float fast_tanh(float x) {
  x = fminf(fmaxf(x, -15.0f), 15.0f);
  float t = __expf(2.0f * x);
  return __fdividef(t - 1.0f, t + 1.0f);
}

__device__ inline short f2bs(float x) {
  bf16 h = __float2bfloat16(x);
  return *reinterpret_cast<short*>(&h);
}
__device__ inline short8 ld8b(const float* p) {
  const float4 a = ((const float4*)p)[0];
  const float4 b = ((const float4*)p)[1];
  short8 r;
  r[0] = f2bs(a.x); r[1] = f2bs(a.y); r[2] = f2bs(a.z); r[3] = f2bs(a.w);
  r[4] = f2bs(b.x); r[5] = f2bs(b.y); r[6] = f2bs(b.z); r[7] = f2bs(b.w);
  return r;
}
__device__ inline short4v ld4b(const float* p) {
  const float4 a = *(const float4*)p;
  short4v r;
  r[0] = f2bs(a.x); r[1] = f2bs(a.y); r[2] = f2bs(a.z); r[3] = f2bs(a.w);
  return r;
}

__device__ inline void async_load16(const bf16* g, short* l) {
  __builtin_amdgcn_global_load_lds(
      (const __attribute__((address_space(1))) unsigned int*)g,
      (__attribute__((address_space(3))) unsigned int*)l, 16, 0, 0);
}

// ---------------- prep: weights -> WT bf16 [N][Kp]; biases; gates; x -> bf16
__global__ __launch_bounds__(256) void prep_all(
    const float* w0, const float* w1, const float* w2, const float* w3,
    const float* w4, const float* w5, const float* w6, const float* w7,
    const float* b0, const float* b1, const float* b2, const float* b3,
    const float* b4, const float* b5, const float* b6, const float* b7,
    const float* dp, const float* xf,
    bf16* __restrict__ wt, float* __restrict__ biasf, float* __restrict__ gw,
    bf16* __restrict__ xb, int do_x) {
  const int bid = blockIdx.x;
  const int tid = threadIdx.x;
  const int Ks[8]  = {2560, 1024, 512, 24, 128, 256, 512, 1024};
  const int Ns[8]  = {1024, 512, 256, 128, 256, 512, 1024, 2560};
  const int cum[8] = {2560, 3072, 3200, 3204, 3236, 3364, 3876, 6436};
  const long wto[8] = {0, 2621440, 3145728, 3276800, 3280896, 3313664, 3444736, 3969024};
  const float* Wp[8] = {w0, w1, w2, w3, w4, w5, w6, w7};
  const float* Bp[8] = {b0, b1, b2, b3, b4, b5, b6, b7};
  const int boff[8] = {0, 1024, 1536, 1792, 1920, 2176, 2688, 3712};

  if (bid < 6436) {
    int t = 0;
    while (bid >= cum[t]) t++;
    int base = t ? cum[t - 1] : 0;
    int local = bid - base;
    int K = Ks[t], N = Ns[t];
    int tk = (K + 31) >> 5;
    int kt = local % tk, nt = local / tk;
    int Kp = tk << 5;
    __shared__ short tile[32][33];
    int r = tid >> 3, c4 = (tid & 7) << 2;
    int gk = kt * 32 + r, gn = nt * 32 + c4;
    short4v v;
    if (gk < K) v = ld4b(Wp[t] + (size_t)gk * N + gn);
    else { v[0] = 0; v[1] = 0; v[2] = 0; v[3] = 0; }
    tile[r][c4] = v[0]; tile[r][c4 + 1] = v[1]; tile[r][c4 + 2] = v[2]; tile[r][c4 + 3] = v[3];
    __syncthreads();
    int n = tid >> 3, k4 = (tid & 7) << 2;
    short4v o;
    o[0] = tile[k4][n]; o[1] = tile[k4 + 1][n]; o[2] = tile[k4 + 2][n]; o[3] = tile[k4 + 3][n];
    *(short4v*)&wt[wto[t] + (size_t)(nt * 32 + n) * Kp + kt * 32 + k4] = o;
  } else if (bid < 6444) {
    int b = bid - 6436;
    int nb = Ns[b];
    for (int t2 = tid; t2 < nb; t2 += 256)
      biasf[boff[b] + t2] = Bp[b][t2];
  } else if (bid == 6444) {
    int g = tid;
    if (g < 48) {
      float phi = dp[g * 3 + 0], theta = dp[g * 3 + 1], omega = dp[g * 3 + 2];
      float c = cosf(0.5f * theta), s = sinf(0.5f * theta);
      float a = 0.5f * (phi + omega), d = 0.5f * (phi - omega);
      float ca = cosf(a), sa = sinf(a), cd = cosf(d), sd = sinf(d);
      float* o = gw + g * 8;
      o[0] =  ca * c; o[1] = -sa * c;
      o[2] = -cd * s; o[3] = -sd * s;
      o[4] =  cd * s; o[5] = -sd * s;
      o[6] =  ca * c; o[7] =  sa * c;
    }
  } else if (do_x) {
    long i = ((long)(bid - 6445) * 256 + tid) * 8;
    if (i < 10485760L) {
      short8 v = ld8b(xf + i);
      *(short8*)((short*)xb + i) = v;
    }
  }
}

// ---------------- async MFMA GEMM: C = act(A @ Bt^T + bias)
// XOR-swizzled LDS chunk layout (round-7: conflicts -> 0).
template <int BM, int BN, int BK, int WR, int WC, int ACT, typename TC>
__global__ __launch_bounds__(256) void gemm_async(const bf16* __restrict__ A,
                                                  const bf16* __restrict__ Bt,
                                                  const float* __restrict__ bias,
                                                  TC* __restrict__ C,
                                                  int M, int N, int K) {
  constexpr int CPR = BK / 8;
  constexpr int MASK = CPR - 1;
  constexpr int RPW = 64 / CPR;
  constexpr int RPP = 4 * RPW;
  constexpr int WMT = BM / WR;
  constexpr int WNT = BN / WC;
  constexpr int FI = WMT / 16;
  constexpr int FJ = WNT / 16;
  constexpr int KK = BK / 32;
  __shared__ __align__(16) short As[BM * BK];
  __shared__ __align__(16) short Bs[BN * BK];
  const int tid = threadIdx.x;
  const int lane = tid & 63;
  const int wid = tid >> 6;
  const int wm = wid / WC, wn = wid % WC;
  const int bm = blockIdx.y * BM;
  const int bn = blockIdx.x * BN;

  const int st_r = lane / CPR;
  const int st_cs = (lane & MASK) ^ (st_r & MASK);

  const int frag_m = lane & 15;
  const int q = lane >> 4;

  f32x4 acc[FI][FJ] = {};

  for (int k0 = 0; k0 < K; k0 += BK) {
#pragma unroll
    for (int p = 0; p < BM / RPP; ++p) {
      const bf16* g = A + (size_t)(bm + p * RPP + wid * RPW + st_r) * K + k0 + st_cs * 8;
      async_load16(g, &As[(p * RPP + wid * RPW) * BK]);
    }
#pragma unroll
    for (int p = 0; p < BN / RPP; ++p) {
      const bf16* g = Bt + (size_t)(bn + p * RPP + wid * RPW + st_r) * K + k0 + st_cs * 8;
      async_load16(g, &Bs[(p * RPP + wid * RPW) * BK]);
    }
    __syncthreads();
    short8 af[FI][KK], bfr[FJ][KK];
#pragma unroll
    for (int i = 0; i < FI; ++i) {
      const int m = wm * WMT + i * 16 + frag_m;
#pragma unroll
      for (int kk = 0; kk < KK; ++kk) {
        const int slot = (kk * 4 + q) ^ (m & MASK);
        af[i][kk] = *(const short8*)&As[m * BK + slot * 8];
      }
    }
#pragma unroll
    for (int j = 0; j < FJ; ++j) {
      const int n = wn * WNT + j * 16 + frag_m;
#pragma unroll
      for (int kk = 0; kk < KK; ++kk) {
        const int slot = (kk * 4 + q) ^ (n & MASK);
        bfr[j][kk] = *(const short8*)&Bs[n * BK + slot * 8];
      }
    }
#pragma unroll
    for (int kk = 0; kk < KK; ++kk)
#pragma unroll
      for (int i = 0; i < FI; ++i)
#pragma unroll
        for (int j = 0; j < FJ; ++j)
          acc[i][j] = __builtin_amdgcn_mfma_f32_16x16x32_bf16(af[i][kk], bfr[j][kk], acc[i][j], 0, 0, 0);
    __syncthreads();
  }

  const int col_lane = lane & 15;
  const int row_quad = q << 2;
#pragma unroll
  for (int i = 0; i < FI; ++i) {
#pragma unroll
    for (int j = 0; j < FJ; ++j) {
      int n = bn + wn * WNT + j * 16 + col_lane;
      float bj = bias[n];
#pragma unroll
      for (int r = 0; r < 4; ++r) {
        int m = bm + wm * WMT + i * 16 + row_quad + r;
        float v = acc[i][j][r] + bj;
        if (ACT == 0) v = (v >= 0.f) ? v : 0.2f * v;
        else v = fast_tanh(v);
        stf(C, (size_t)m * N + n, v);
      }
    }
  }
}

// ---------------- fallback GEMM1 (f32 A and W) — used only if ws too small
__global__ __launch_bounds__(256) void gemm_cvt(const float* __restrict__ A,
                                                const float* __restrict__ W,
                                                const float* __restrict__ bias,
                                                bf16* __restrict__ C,
                                                int M, int N, int K) {
  __shared__ __align__(16) short As[128 * 40];
  __shared__ __align__(16) short Bs[128 * 40];
  const int tid = threadIdx.x;
  const int lane = tid & 63;
  const int wave = tid >> 6;
  const int wm = wave >> 1, wn = wave & 1;
  const int bm = blockIdx.y * 128;
  const int bn = blockIdx.x * 128;
  const int a_row0 = tid >> 2;
  const int a_kcol = (tid & 3) << 3;
  const int b_ncol = (tid & 31) << 2;
  const int b_krow = (tid >> 5) << 2;
  const int frag_m = lane & 15;
  const int frag_k = (lane >> 4) << 3;

  f32x4 acc[4][4] = {};

  for (int k0 = 0; k0 < K; k0 += 32) {
#pragma unroll
    for (int c = 0; c < 2; ++c) {
      const int row = c * 64 + a_row0;
      short8 v = ld8b(A + (size_t)(bm + row) * K + k0 + a_kcol);
      *(short8*)&As[row * 40 + a_kcol] = v;
    }
    short4v bv[4];
#pragma unroll
    for (int kk = 0; kk < 4; ++kk)
      bv[kk] = ld4b(W + (size_t)(k0 + b_krow + kk) * N + bn + b_ncol);
#pragma unroll
    for (int nn = 0; nn < 4; ++nn) {
      short4v w;
      w[0] = bv[0][nn]; w[1] = bv[1][nn]; w[2] = bv[2][nn]; w[3] = bv[3][nn];
      *(short4v*)&Bs[(b_ncol + nn) * 40 + b_krow] = w;
    }
    __syncthreads();
    short8 af[4], bfr[4];
#pragma unroll
    for (int i = 0; i < 4; ++i)
      af[i] = *(const short8*)&As[(wm * 64 + i * 16 + frag_m) * 40 + frag_k];
#pragma unroll
    for (int j = 0; j < 4; ++j)
      bfr[j] = *(const short8*)&Bs[(wn * 64 + j * 16 + frag_m) * 40 + frag_k];
#pragma unroll
    for (int i = 0; i < 4; ++i)
#pragma unroll
      for (int j = 0; j < 4; ++j)
        acc[i][j] = __builtin_amdgcn_mfma_f32_16x16x32_bf16(af[i], bfr[j], acc[i][j], 0, 0, 0);
    __syncthreads();
  }

  const int col_lane = lane & 15;
  const int row_quad = (lane >> 4) << 2;
#pragma unroll
  for (int i = 0; i < 4; ++i)
#pragma unroll
    for (int j = 0; j < 4; ++j) {
      int n = bn + wn * 64 + j * 16 + col_lane;
      float bj = bias[n];
#pragma unroll
      for (int r = 0; r < 4; ++r) {
        int m = bm + wm * 64 + i * 16 + row_quad + r;
        float v = acc[i][j][r] + bj;
        v = (v >= 0.f) ? v : 0.2f * v;
        stf(C, (size_t)m * N + n, v);
      }
    }
}

// ---------------- circuit + fused d1: 1 wave per batch element.
// After full-butterfly reductions every lane holds all 24 expectation
// values; each lane then computes 2 of d1's 128 outputs directly.
__global__ __launch_bounds__(256) void circuit_wave(const float* __restrict__ enc,
                                                    const float* __restrict__ gw,
                                                    const float* __restrict__ dw1,
                                                    const float* __restrict__ db1,
                                                    bf16* __restrict__ d1out) {
  __shared__ float gsh[384];
  const int tid = threadIdx.x;
  for (int t = tid; t < 384; t += 256) gsh[t] = gw[t];
  __syncthreads();
  const int lane = tid & 63;
  const int b = blockIdx.x * 4 + (tid >> 6);

  float4 e = *(const float4*)(enc + (size_t)b * 256 + lane * 4);
  float re[4] = {e.x, e.y, e.z, e.w};
  float im[4] = {0.f, 0.f, 0.f, 0.f};
  float ss = e.x * e.x + e.y * e.y + e.z * e.z + e.w * e.w;
#pragma unroll
  for (int o = 32; o; o >>= 1) ss += __shfl_xor(ss, o, 64);
  float inv = 1.0f / fmaxf(sqrtf(ss), 1e-12f);
#pragma unroll
  for (int j = 0; j < 4; ++j) re[j] *= inv;

  for (int l = 0; l < 6; ++l) {
    for (int qq = 0; qq < 8; ++qq) {
      const float* g = &gsh[(l * 8 + qq) * 8];
      const int s = 1 << (7 - qq);
      if (s >= 4) {
        const int lm = s >> 2;
        const bool hi = (lane & lm) != 0;
        const float g0r = hi ? g[4] : g[0], g0i = hi ? g[5] : g[1];
        const float g1r = hi ? g[6] : g[2], g1i = hi ? g[7] : g[3];
#pragma unroll
        for (int j = 0; j < 4; ++j) {
          float orr = __shfl_xor(re[j], lm, 64);
          float oii = __shfl_xor(im[j], lm, 64);
          float p0r = hi ? orr : re[j], p0i = hi ? oii : im[j];
          float p1r = hi ? re[j] : orr, p1i = hi ? im[j] : oii;
          re[j] = g0r * p0r - g0i * p0i + g1r * p1r - g1i * p1i;
          im[j] = g0r * p0i + g0i * p0r + g1r * p1i + g1i * p1r;
        }
      } else {
#pragma unroll
        for (int j0 = 0; j0 < 4; ++j0) {
          if ((j0 & s) == 0) {
            int j1 = j0 | s;
            float p0r = re[j0], p0i = im[j0], p1r = re[j1], p1i = im[j1];
            re[j0] = g[0] * p0r - g[1] * p0i + g[2] * p1r - g[3] * p1i;
            im[j0] = g[0] * p0i + g[1] * p0r + g[2] * p1i + g[3] * p1r;
            re[j1] = g[4] * p0r - g[5] * p0i + g[6] * p1r - g[7] * p1i;
            im[j1] = g[4] * p0i + g[5] * p0r + g[6] * p1i + g[7] * p1r;
          }
        }
      }
    }
    const int r = l % 7 + 1;
    for (int qq = 0; qq < 8; ++qq) {
      const int sc = 1 << (7 - qq);
      const int st = 1 << (7 - ((qq + r) & 7));
      if (st >= 4) {
        const int lm = st >> 2;
        if (sc >= 4) {
          const bool ctl = (lane & (sc >> 2)) != 0;
#pragma unroll
          for (int j = 0; j < 4; ++j) {
            float orr = __shfl_xor(re[j], lm, 64);
            float oii = __shfl_xor(im[j], lm, 64);
            re[j] = ctl ? orr : re[j];
            im[j] = ctl ? oii : im[j];
          }
        } else {
#pragma unroll
          for (int j = 0; j < 4; ++j) {
            if (j & sc) {
              re[j] = __shfl_xor(re[j], lm, 64);
              im[j] = __shfl_xor(im[j], lm, 64);
            }
          }
        }
      } else {
        if (sc >= 4) {
          const bool ctl = (lane & (sc >> 2)) != 0;
#pragma unroll
          for (int j0 = 0; j0 < 4; ++j0) {
            if ((j0 & st) == 0) {
              int j1 = j0 | st;
              float t0r = re[j0], t0i = im[j0];
              float t1r = re[j1], t1i = im[j1];
              re[j0] = ctl ? t1r : t0r; im[j0] = ctl ? t1i : t0i;
              re[j1] = ctl ? t0r : t1r; im[j1] = ctl ? t0i : t1i;
            }
          }
        } else {
#pragma unroll
          for (int j0 = 0; j0 < 4; ++j0) {
            if ((j0 & sc) && (j0 & st) == 0) {
              int j1 = j0 | st;
              float tr = re[j0], ti = im[j0];
              re[j0] = re[j1]; im[j0] = im[j1];
              re[j1] = tr; im[j1] = ti;
            }
          }
        }
      }
    }
  }

  float mz[8], mx[8], my[8];
#pragma unroll
  for (int qq = 0; qq < 8; ++qq) {
    const int s = 1 << (7 - qq);
    float z = 0.f, x = 0.f, y = 0.f;
#pragma unroll
    for (int j = 0; j < 4; ++j) {
      float fr, fi;
      if (s >= 4) {
        fr = __shfl_xor(re[j], s >> 2, 64);
        fi = __shfl_xor(im[j], s >> 2, 64);
      } else {
        fr = re[j ^ s]; fi = im[j ^ s];
      }
      float prob = re[j] * re[j] + im[j] * im[j];
      int i = lane * 4 + j;
      float sg = (i & s) ? -1.f : 1.f;
      z += sg * prob;
      x += re[j] * fr + im[j] * fi;
      y += sg * (re[j] * fi - im[j] * fr);
    }
#pragma unroll
    for (int o = 32; o; o >>= 1) {
      z += __shfl_xor(z, o, 64);
      x += __shfl_xor(x, o, 64);
      y += __shfl_xor(y, o, 64);
    }
    mz[qq] = z; mx[qq] = x; my[qq] = y;
  }

  // fused d1: leaky(meas @ dw1 + db1), dw1 f32 [24][128]
#pragma unroll
  for (int half = 0; half < 2; ++half) {
    const int n = lane + half * 64;
    float acc = db1[n];
#pragma unroll
    for (int qq = 0; qq < 8; ++qq) {
      acc += mz[qq] * dw1[qq * 128 + n];
      acc += mx[qq] * dw1[(8 + qq) * 128 + n];
      acc += my[qq] * dw1[(16 + qq) * 128 + n];
    }
    acc = (acc >= 0.f) ? acc : 0.2f * acc;
    d1out[(size_t)b * 128 + n] = __float2bfloat16(acc);
  }
}

extern "C" void kernel_launch(void* const* d_in, const int* in_sizes, int n_in,
                              void* d_out, int out_size, void* d_ws, size_t ws_size,
                              hipStream_t stream) {
  (void)in_sizes; (void)n_in; (void)out_size;
  char* wsb = (char*)d_ws;
  float* gw    = (float*)(wsb + 256);
  float* biasf = (float*)(wsb + 4096);
  float* encf  = (float*)(wsb + 294912);
  bf16*  P     = (bf16*)(wsb + 4489216);
  bf16*  Q     = (bf16*)(wsb + 12877824);
  bf16*  WT    = (bf16*)(wsb + 17072128);
  bf16*  Xb    = (bf16*)(wsb + 30253056);
  const bool have_xb = ws_size >= 51224576;

  bf16* ew1t = WT + 0;
  bf16* ew2t = WT + 2621440;
  bf16* ew3t = WT + 3145728;
  bf16* dw2t = WT + 3280896;
  bf16* dw3t = WT + 3313664;
  bf16* dw4t = WT + 3444736;
  bf16* dw5t = WT + 3969024;
  float* beb1 = biasf + 0;
  float* beb2 = biasf + 1024;
  float* beb3 = biasf + 1536;
  float* bdb2 = biasf + 1920;
  float* bdb3 = biasf + 2176;
  float* bdb4 = biasf + 2688;
  float* bdb5 = biasf + 3712;

  prep_all<<<11565, 256, 0, stream>>>(
      (const float*)d_in[1], (const float*)d_in[3], (const float*)d_in[5],
      (const float*)d_in[8], (const float*)d_in[10], (const float*)d_in[12],
      (const float*)d_in[14], (const float*)d_in[16],
      (const float*)d_in[2], (const float*)d_in[4], (const float*)d_in[6],
      (const float*)d_in[9], (const float*)d_in[11], (const float*)d_in[13],
      (const float*)d_in[15], (const float*)d_in[17],
      (const float*)d_in[7], (const float*)d_in[0],
      WT, biasf, gw, Xb, have_xb ? 1 : 0);

  // ---- GEMM1: h1 = leaky(x @ ew1 + eb1)   [4096x1024, K=2560]
  if (have_xb) {
    gemm_async<128, 64, 64, 4, 1, 0, bf16><<<dim3(16, 32), 256, 0, stream>>>(
        Xb, ew1t, beb1, P, 4096, 1024, 2560);
  } else {
    gemm_cvt<<<dim3(8, 32), 256, 0, stream>>>(
        (const float*)d_in[0], (const float*)d_in[1], beb1, P, 4096, 1024, 2560);
  }

  // ---- GEMM2: h2 = leaky(h1 @ ew2 + eb2)  [4096x512, K=1024]
  gemm_async<64, 64, 64, 2, 2, 0, bf16><<<dim3(8, 64), 256, 0, stream>>>(
      P, ew2t, beb2, Q, 4096, 512, 1024);
  // ---- GEMM3: enc = tanh(h2 @ ew3 + eb3)  [4096x256, K=512] -> f32
  gemm_async<64, 64, 64, 2, 2, 1, float><<<dim3(4, 64), 256, 0, stream>>>(
      Q, ew3t, beb3, encf, 4096, 256, 512);

  // ---- circuit + fused d1 -> Q bf16 [4096][128]
  circuit_wave<<<1024, 256, 0, stream>>>(encf, gw, (const float*)d_in[8],
                                         (const float*)d_in[9], Q);

  // ---- decoder
  gemm_async<64, 64, 64, 2, 2, 0, bf16><<<dim3(4, 64), 256, 0, stream>>>(
      Q, dw2t, bdb2, P, 4096, 256, 128);
  gemm_async<64, 64, 64, 2, 2, 0, bf16><<<dim3(8, 64), 256, 0, stream>>>(
      P, dw3t, bdb3, Q, 4096, 512, 256);
  gemm_async<128, 64, 64, 4, 1, 0, bf16><<<dim3(16, 32), 256, 0, stream>>>(
      Q, dw4t, bdb4, P, 4096, 1024, 512);
  // ---- d5: out = tanh(d4 @ dw5 + db5)  [4096x2560, K=1024] -> f32
  gemm_async<128, 128, 64, 2, 2, 1, float><<<dim3(20, 32), 256, 0, stream>>>(
      P, dw5t, bdb5, (float*)d_out, 4096, 2560, 1024);
}